// Round 5
// baseline (466.650 us; speedup 1.0000x reference)
//
#include <hip/hip_runtime.h>
#include <cmath>

#define EPSF 1e-7f

constexpr int B_ = 4, S_ = 1024, E_ = 1024, H_ = 16, D_ = 64;
constexpr int BS_ = B_ * S_;   // 4096 rows per matrix

typedef __attribute__((ext_vector_type(8))) short bf16x8;
typedef __attribute__((ext_vector_type(4))) float f32x4;

__device__ inline unsigned int fbits(float f) { union { float f; unsigned int u; } x; x.f = f; return x.u; }
__device__ inline float ubits(unsigned int u) { union { unsigned int u; float f; } x; x.u = u; return x.f; }

__device__ inline unsigned short f2bf(float f) {
  unsigned int u = fbits(f);
  unsigned int r = u + 0x7fffu + ((u >> 16) & 1u);   // RNE
  return (unsigned short)(r >> 16);
}
__device__ inline float bf2f(unsigned short h) { return ubits(((unsigned int)h) << 16); }
__device__ inline float fastrcp(float x) { return __builtin_amdgcn_rcpf(x); }

__device__ inline unsigned int packhi(float a, float b) {
  return (fbits(a) >> 16) | (fbits(b) & 0xFFFF0000u);
}
__device__ inline unsigned int packlo(float a, float b) {
  float la = a - ubits(fbits(a) & 0xFFFF0000u);
  float lb = b - ubits(fbits(b) & 0xFFFF0000u);
  return (fbits(la) >> 16) | (fbits(lb) & 0xFFFF0000u);
}

// ---------------- kernel 1: per-row lambda of the three inputs ----------------
__global__ __launch_bounds__(256) void row_lam_kernel(
    const float* __restrict__ xq, const float* __restrict__ xk,
    const float* __restrict__ xv, float* __restrict__ lamRow) {
  int row = blockIdx.x * 4 + (threadIdx.x >> 6);
  int lane = threadIdx.x & 63;
  const float* x = (row < BS_) ? xq : (row < 2 * BS_ ? xk : xv);
  int r = row & (BS_ - 1);
  const float4* xr = (const float4*)(x + (size_t)r * E_);
  float s = 0.f;
  #pragma unroll
  for (int i = 0; i < 4; i++) {
    float4 t = xr[lane + i * 64];
    s += t.x * t.x + t.y * t.y + t.z * t.z + t.w * t.w;
  }
  #pragma unroll
  for (int m = 1; m < 64; m <<= 1) s += __shfl_xor(s, m, 64);
  if (lane == 0) lamRow[row] = 2.0f / fmaxf(1.0f - s, EPSF);
}

// ---------------- kernel 2: column norms of z, cosh/sinh of 2*bias ----------------
__global__ __launch_bounds__(256) void col_stats_kernel(
    const float* __restrict__ zq, const float* __restrict__ zk, const float* __restrict__ zv,
    const float* __restrict__ bq, const float* __restrict__ bk, const float* __restrict__ bv,
    float* __restrict__ znA, float* __restrict__ chA, float* __restrict__ shA) {
  int mat = blockIdx.x >> 4;
  int c0 = (blockIdx.x & 15) * 64;
  const float* z = mat == 0 ? zq : (mat == 1 ? zk : zv);
  const float* bb = mat == 0 ? bq : (mat == 1 ? bk : bv);
  int col = c0 + (threadIdx.x & 63);
  int r0 = threadIdx.x >> 6;
  float s = 0.f;
  for (int rr = r0; rr < E_; rr += 4) {
    float t = z[(size_t)rr * E_ + col];
    s += t * t;
  }
  __shared__ float red[4][64];
  red[r0][threadIdx.x & 63] = s;
  __syncthreads();
  if (r0 == 0) {
    int l = threadIdx.x;
    s = red[0][l] + red[1][l] + red[2][l] + red[3][l];
    float n = fmaxf(sqrtf(s), 1e-15f);
    int idx = mat * E_ + col;
    znA[idx] = n;
    float rb = bb[col];
    chA[idx] = coshf(2.f * rb);
    shA[idx] = sinhf(2.f * rb);
  }
}

// ---------------- kernel 2b: transpose + hi/lo split of z -> BT[n][k] bf16 ----------------
__global__ __launch_bounds__(256) void zsplit_kernel(
    const float* __restrict__ zq, const float* __restrict__ zk, const float* __restrict__ zv,
    unsigned short* __restrict__ BhiT, unsigned short* __restrict__ BloT) {
  const int mat = blockIdx.z;
  const float* z = mat == 0 ? zq : (mat == 1 ? zk : zv);
  const int k0 = blockIdx.y * 64, n0 = blockIdx.x * 64;
  __shared__ float t[64][65];
  const int tid = threadIdx.x;
  {
    int kr = tid >> 4, nc = (tid & 15) * 4;
    #pragma unroll
    for (int i = 0; i < 4; i++) {
      float4 vv = *(const float4*)(z + (size_t)(k0 + kr + i * 16) * E_ + n0 + nc);
      t[kr + i * 16][nc + 0] = vv.x;
      t[kr + i * 16][nc + 1] = vv.y;
      t[kr + i * 16][nc + 2] = vv.z;
      t[kr + i * 16][nc + 3] = vv.w;
    }
  }
  __syncthreads();
  int nr = tid >> 2, kc = (tid & 3) * 16;
  unsigned int ph[8], pl[8];
  #pragma unroll
  for (int p = 0; p < 8; p++) {
    float x0 = t[kc + 2 * p][nr], x1 = t[kc + 2 * p + 1][nr];
    ph[p] = packhi(x0, x1);
    pl[p] = packlo(x0, x1);
  }
  size_t off = (size_t)mat * E_ * E_ + (size_t)(n0 + nr) * E_ + k0 + kc;
  uint4* dh = (uint4*)(BhiT + off);
  uint4* dl = (uint4*)(BloT + off);
  dh[0] = make_uint4(ph[0], ph[1], ph[2], ph[3]);
  dh[1] = make_uint4(ph[4], ph[5], ph[6], ph[7]);
  dl[0] = make_uint4(pl[0], pl[1], pl[2], pl[3]);
  dl[1] = make_uint4(pl[4], pl[5], pl[6], pl[7]);
}

// ---------------- kernel 3: split-bf16 MFMA GEMM + hlinear epilogue -> bf16 W ----------------
__global__ __launch_bounds__(256, 3) void hlinear_mfma_kernel(
    const float* __restrict__ xq, const float* __restrict__ xk, const float* __restrict__ xv,
    const unsigned short* __restrict__ BhiT, const unsigned short* __restrict__ BloT,
    const float* __restrict__ lamRow, const float* __restrict__ znA,
    const float* __restrict__ chA, const float* __restrict__ shA,
    unsigned short* __restrict__ Wbf) {
  const int mat = blockIdx.z;
  const float* x = mat == 0 ? xq : (mat == 1 ? xk : xv);
  const unsigned short* bh = BhiT + (size_t)mat * E_ * E_;
  const unsigned short* bl = BloT + (size_t)mat * E_ * E_;
  // 4x4 block-square swizzle: concurrent window of 16 blocks shares 4 A-tiles + 4 B-tiles in L2
  const int lid = blockIdx.y * 8 + blockIdx.x;   // grid (8, 32, 3)
  const int sq = lid >> 4, off = lid & 15;
  const int m0 = ((sq >> 1) * 4 + (off & 3)) * 128;
  const int n0 = ((sq & 1) * 4 + (off >> 2)) * 128;

  __shared__ unsigned short Ah[128][40];
  __shared__ unsigned short Al[128][40];
  __shared__ unsigned short Bh[128][40];
  __shared__ unsigned short Bl[128][40];

  const int tid = threadIdx.x;
  const int wid = tid >> 6, lane = tid & 63, quad = lane >> 4, l16 = lane & 15;
  const int wm = (wid >> 1) * 64, wn = (wid & 1) * 64;

  f32x4 acc[4][4];
  #pragma unroll
  for (int i = 0; i < 4; i++)
    #pragma unroll
    for (int j = 0; j < 4; j++) acc[i][j] = (f32x4){0.f, 0.f, 0.f, 0.f};

  const int arow = tid >> 1, ahalf = (tid & 1) * 16;
  const float* aptr = x + (size_t)(m0 + arow) * E_ + ahalf;
  const unsigned short* bhptr = bh + (size_t)(n0 + arow) * E_ + ahalf;
  const unsigned short* blptr = bl + (size_t)(n0 + arow) * E_ + ahalf;

  float4 Ar[4];
  uint4 Brh[2], Brl[2];
  #pragma unroll
  for (int i = 0; i < 4; i++) Ar[i] = *(const float4*)(aptr + i * 4);
  Brh[0] = *(const uint4*)(bhptr);     Brh[1] = *(const uint4*)(bhptr + 8);
  Brl[0] = *(const uint4*)(blptr);     Brl[1] = *(const uint4*)(blptr + 8);

  for (int kt = 0; kt < E_ / 32; ++kt) {
    __syncthreads();
    unsigned int uh[8], ul[8];
    #pragma unroll
    for (int i = 0; i < 4; i++) {
      float4 f = Ar[i];
      uh[2 * i] = packhi(f.x, f.y); uh[2 * i + 1] = packhi(f.z, f.w);
      ul[2 * i] = packlo(f.x, f.y); ul[2 * i + 1] = packlo(f.z, f.w);
    }
    *(uint4*)&Ah[arow][ahalf]     = make_uint4(uh[0], uh[1], uh[2], uh[3]);
    *(uint4*)&Ah[arow][ahalf + 8] = make_uint4(uh[4], uh[5], uh[6], uh[7]);
    *(uint4*)&Al[arow][ahalf]     = make_uint4(ul[0], ul[1], ul[2], ul[3]);
    *(uint4*)&Al[arow][ahalf + 8] = make_uint4(ul[4], ul[5], ul[6], ul[7]);
    *(uint4*)&Bh[arow][ahalf]     = Brh[0];
    *(uint4*)&Bh[arow][ahalf + 8] = Brh[1];
    *(uint4*)&Bl[arow][ahalf]     = Brl[0];
    *(uint4*)&Bl[arow][ahalf + 8] = Brl[1];
    if (kt < E_ / 32 - 1) {
      int k0 = (kt + 1) * 32;
      #pragma unroll
      for (int i = 0; i < 4; i++) Ar[i] = *(const float4*)(aptr + k0 + i * 4);
      Brh[0] = *(const uint4*)(bhptr + k0);     Brh[1] = *(const uint4*)(bhptr + k0 + 8);
      Brl[0] = *(const uint4*)(blptr + k0);     Brl[1] = *(const uint4*)(blptr + k0 + 8);
    }
    __syncthreads();
    bf16x8 ah[4], al[4];
    #pragma unroll
    for (int mt = 0; mt < 4; mt++) {
      ah[mt] = *(const bf16x8*)&Ah[wm + mt * 16 + l16][quad * 8];
      al[mt] = *(const bf16x8*)&Al[wm + mt * 16 + l16][quad * 8];
    }
    #pragma unroll
    for (int nt = 0; nt < 4; nt++) {
      bf16x8 bhf = *(const bf16x8*)&Bh[wn + nt * 16 + l16][quad * 8];
      bf16x8 blf = *(const bf16x8*)&Bl[wn + nt * 16 + l16][quad * 8];
      #pragma unroll
      for (int mt = 0; mt < 4; mt++) {
        acc[mt][nt] = __builtin_amdgcn_mfma_f32_16x16x32_bf16(ah[mt], bhf, acc[mt][nt], 0, 0, 0);
        acc[mt][nt] = __builtin_amdgcn_mfma_f32_16x16x32_bf16(ah[mt], blf, acc[mt][nt], 0, 0, 0);
        acc[mt][nt] = __builtin_amdgcn_mfma_f32_16x16x32_bf16(al[mt], bhf, acc[mt][nt], 0, 0, 0);
      }
    }
  }

  const float* lamP = lamRow + mat * BS_;
  float lamv[16];
  #pragma unroll
  for (int mt = 0; mt < 4; mt++)
    #pragma unroll
    for (int r = 0; r < 4; r++)
      lamv[mt * 4 + r] = lamP[m0 + wm + mt * 16 + quad * 4 + r];
  unsigned short* out = Wbf + (size_t)mat * BS_ * E_;
  #pragma unroll
  for (int nt = 0; nt < 4; nt++) {
    int cg = n0 + wn + nt * 16 + l16;
    float zn = znA[mat * E_ + cg];
    float chzn = chA[mat * E_ + cg] / zn;
    float sh = shA[mat * E_ + cg];
    float tzn = 2.f * zn;
    #pragma unroll
    for (int mt = 0; mt < 4; mt++) {
      #pragma unroll
      for (int r = 0; r < 4; r++) {
        float lam = lamv[mt * 4 + r];
        float arg = fmaf(lam * acc[mt][nt][r], chzn, -(lam - 1.f) * sh);
        float sq2 = sqrtf(fmaf(arg, arg, 1.f));
        float v = tzn * __logf(arg + sq2);
        float w = 0.5f * (__expf(v) - __expf(-v));
        out[(size_t)(m0 + wm + mt * 16 + quad * 4 + r) * E_ + cg] = f2bf(w);
      }
    }
  }
}

// ---------------- kernel 4: normalize bf16 w -> bf16 P + per-head squared norms ----------------
__global__ __launch_bounds__(256) void normalize_kernel(
    const unsigned short* __restrict__ Wbf, unsigned short* __restrict__ Pbf,
    float* __restrict__ HN) {
  const unsigned short* w = Wbf + (size_t)blockIdx.x * E_;
  int tid = threadIdx.x;
  uint2 wv = ((const uint2*)w)[tid];   // 4 bf16
  float w0 = bf2f((unsigned short)(wv.x & 0xFFFF));
  float w1 = bf2f((unsigned short)(wv.x >> 16));
  float w2 = bf2f((unsigned short)(wv.y & 0xFFFF));
  float w3 = bf2f((unsigned short)(wv.y >> 16));
  float s = w0 * w0 + w1 * w1 + w2 * w2 + w3 * w3;
  #pragma unroll
  for (int m = 1; m < 64; m <<= 1) s += __shfl_xor(s, m, 64);
  __shared__ float red[4];
  if ((tid & 63) == 0) red[tid >> 6] = s;
  __syncthreads();
  s = red[0] + red[1] + red[2] + red[3];
  float t = 1.f / (1.f + sqrtf(1.f + s));
  unsigned short p0 = f2bf(w0 * t), p1 = f2bf(w1 * t), p2 = f2bf(w2 * t), p3 = f2bf(w3 * t);
  uint2 pk;
  pk.x = (unsigned int)p0 | ((unsigned int)p1 << 16);
  pk.y = (unsigned int)p2 | ((unsigned int)p3 << 16);
  ((uint2*)(Pbf + (size_t)blockIdx.x * E_))[tid] = pk;
  float r0 = bf2f(p0), r1 = bf2f(p1), r2 = bf2f(p2), r3 = bf2f(p3);
  float hs = r0 * r0 + r1 * r1 + r2 * r2 + r3 * r3;
  hs += __shfl_xor(hs, 1, 64);
  hs += __shfl_xor(hs, 2, 64);
  hs += __shfl_xor(hs, 4, 64);
  hs += __shfl_xor(hs, 8, 64);
  if ((tid & 15) == 0) HN[(size_t)blockIdx.x * H_ + (tid >> 4)] = hs;
}

// ---------------- kernel 5: MFMA flash hyperbolic attention ----------------
__global__ __launch_bounds__(512) void attention_kernel(
    const unsigned short* __restrict__ Pbf, const float* __restrict__ HN,
    float* __restrict__ TV, float scale) {
  const int qt = blockIdx.x, h = blockIdx.y, b = blockIdx.z;
  const unsigned short* pq = Pbf;
  const unsigned short* pk = Pbf + (size_t)BS_ * E_;
  const unsigned short* pv = Pbf + (size_t)2 * BS_ * E_;
  const float* hnq = HN;
  const float* hnk = HN + (size_t)BS_ * H_;
  const float* hnv = HN + (size_t)2 * BS_ * H_;

  const int tid = threadIdx.x;
  const int wid = tid >> 6, lane = tid & 63;
  const int quad = lane >> 4, l16 = lane & 15;

  __shared__ unsigned short Kbf[64][72];
  __shared__ unsigned short Vt[64][72];
  __shared__ unsigned short Pw[8][16][72];
  __shared__ float k2s[64], romk2s[64], lamLs[64];

  const int qrow0 = qt * 128 + wid * 16;
  const size_t qgrow = ((size_t)(b * S_ + qrow0 + l16)) * E_ + h * 64;
  bf16x8 aq0 = *(const bf16x8*)(pq + qgrow + quad * 8);
  bf16x8 aq1 = *(const bf16x8*)(pq + qgrow + 32 + quad * 8);
  float q2r[4], tromq2[4];
  #pragma unroll
  for (int r2 = 0; r2 < 4; r2++) {
    float q2 = hnq[((size_t)(b * S_ + qrow0 + quad * 4 + r2)) * H_ + h];
    q2r[r2] = q2;
    tromq2[r2] = 2.f * fastrcp(1.f - q2);
  }

  float aWL[4] = {0.f, 0.f, 0.f, 0.f};
  float aW[4]  = {0.f, 0.f, 0.f, 0.f};
  f32x4 accO[4];
  #pragma unroll
  for (int dt = 0; dt < 4; dt++) accO[dt] = (f32x4){0.f, 0.f, 0.f, 0.f};

  for (int kt = 0; kt < S_ / 64; ++kt) {
    __syncthreads();
    {
      int row = tid >> 3, col = (tid & 7) * 8;
      const uint4* src = (const uint4*)(pk + ((size_t)(b * S_ + kt * 64 + row)) * E_ + h * 64 + col);
      *(uint4*)&Kbf[row][col] = *src;
    }
    if (tid < 64) {
      float k2 = hnk[((size_t)(b * S_ + kt * 64 + tid)) * H_ + h];
      k2s[tid] = k2;
      romk2s[tid] = fastrcp(1.f - k2);
      float v2 = hnv[((size_t)(b * S_ + kt * 64 + tid)) * H_ + h];
      lamLs[tid] = 2.f / fmaxf(1.f - v2, EPSF);
    }
    {
      int key = tid & 63, dg = tid >> 6;
      union { uint4 q; unsigned short u[8]; } vv;
      vv.q = *(const uint4*)(pv + ((size_t)(b * S_ + kt * 64 + key)) * E_ + h * 64 + dg * 8);
      #pragma unroll
      for (int d = 0; d < 8; d++)
        Vt[dg * 8 + d][key] = vv.u[d];
    }
    __syncthreads();

    #pragma unroll
    for (int nt = 0; nt < 4; nt++) {
      bf16x8 bk0 = *(const bf16x8*)&Kbf[nt * 16 + l16][quad * 8];
      bf16x8 bk1 = *(const bf16x8*)&Kbf[nt * 16 + l16][32 + quad * 8];
      f32x4 z = (f32x4){0.f, 0.f, 0.f, 0.f};
      f32x4 d0 = __builtin_amdgcn_mfma_f32_16x16x32_bf16(aq0, bk0, z, 0, 0, 0);
      d0 = __builtin_amdgcn_mfma_f32_16x16x32_bf16(aq1, bk1, d0, 0, 0, 0);
      float k2 = k2s[nt * 16 + l16];
      float romk2 = romk2s[nt * 16 + l16];
      float lamL = lamLs[nt * 16 + l16];
      #pragma unroll
      for (int r2 = 0; r2 < 4; r2++) {
        float diff2 = fmaf(-2.f, d0[r2], q2r[r2] + k2);
        float t = fmaxf(diff2 * (tromq2[r2] * romk2), 1e-6f);
        float w = fastrcp((1.f + t) + sqrtf(fmaf(t, t, t + t)));
        float wl = w * lamL;
        Pw[wid][quad * 4 + r2][nt * 16 + l16] = f2bf(wl);
        aWL[r2] += wl;
        aW[r2] += w;
      }
    }
    bf16x8 ap0 = *(const bf16x8*)&Pw[wid][l16][quad * 8];
    bf16x8 ap1 = *(const bf16x8*)&Pw[wid][l16][32 + quad * 8];
    #pragma unroll
    for (int dt = 0; dt < 4; dt++) {
      bf16x8 bv0 = *(const bf16x8*)&Vt[dt * 16 + l16][quad * 8];
      bf16x8 bv1 = *(const bf16x8*)&Vt[dt * 16 + l16][32 + quad * 8];
      accO[dt] = __builtin_amdgcn_mfma_f32_16x16x32_bf16(ap0, bv0, accO[dt], 0, 0, 0);
      accO[dt] = __builtin_amdgcn_mfma_f32_16x16x32_bf16(ap1, bv1, accO[dt], 0, 0, 0);
    }
  }

  #pragma unroll
  for (int r2 = 0; r2 < 4; r2++) {
    float dsum = aWL[r2] - aW[r2];
    dsum += __shfl_xor(dsum, 1, 64);
    dsum += __shfl_xor(dsum, 2, 64);
    dsum += __shfl_xor(dsum, 4, 64);
    dsum += __shfl_xor(dsum, 8, 64);
    float uu[4];
    float su = 0.f;
    #pragma unroll
    for (int dt = 0; dt < 4; dt++) { uu[dt] = accO[dt][r2] / dsum; su += uu[dt] * uu[dt]; }
    su += __shfl_xor(su, 1, 64);
    su += __shfl_xor(su, 2, 64);
    su += __shfl_xor(su, 4, 64);
    su += __shfl_xor(su, 8, 64);
    float g = 1.f / (1.f + sqrtf(fmaxf(1.f - su, EPSF)));
    float n2 = fmaxf(su * g * g, 1e-15f);
    float n = sqrtf(n2);
    float fac = atanhf(fminf(n, 1.f - 1e-6f)) / n * g * scale;
    size_t orow = ((size_t)(b * S_ + qrow0 + quad * 4 + r2)) * E_ + h * 64 + l16;
    #pragma unroll
    for (int dt = 0; dt < 4; dt++) TV[orow + dt * 16] = fac * uu[dt];
  }
}

// ---------------- kernel 6: expmap0 per full E-row, in-place on d_out ----------------
__global__ __launch_bounds__(256) void expmap_kernel(float* __restrict__ TV) {
  float* w = TV + (size_t)blockIdx.x * E_;
  int tid = threadIdx.x;
  float4 v = ((float4*)w)[tid];
  float s = v.x * v.x + v.y * v.y + v.z * v.z + v.w * v.w;
  #pragma unroll
  for (int m = 1; m < 64; m <<= 1) s += __shfl_xor(s, m, 64);
  __shared__ float red[4];
  if ((tid & 63) == 0) red[tid >> 6] = s;
  __syncthreads();
  s = red[0] + red[1] + red[2] + red[3];
  float n = sqrtf(fmaxf(s, 1e-15f));
  float f = tanhf(n) / n;
  v.x *= f; v.y *= f; v.z *= f; v.w *= f;
  ((float4*)w)[tid] = v;
}

extern "C" void kernel_launch(void* const* d_in, const int* in_sizes, int n_in,
                              void* d_out, int out_size, void* d_ws, size_t ws_size,
                              hipStream_t stream) {
  (void)in_sizes; (void)n_in; (void)out_size; (void)ws_size;
  const float* q  = (const float*)d_in[0];
  const float* k  = (const float*)d_in[1];
  const float* v  = (const float*)d_in[2];
  const float* zq = (const float*)d_in[3];
  const float* bq = (const float*)d_in[4];
  const float* zk = (const float*)d_in[5];
  const float* bk = (const float*)d_in[6];
  const float* zv = (const float*)d_in[7];
  const float* bv = (const float*)d_in[8];

  unsigned short* Wbf = (unsigned short*)d_ws;                       // 3*BS*E bf16 (25.2 MB)
  unsigned short* Pbf = Wbf + (size_t)3 * BS_ * E_;                  // 3*BS*E bf16 (25.2 MB)
  unsigned short* BhiT = Pbf;                                        // aliases Pbf (dead until normalize)
  unsigned short* BloT = Pbf + (size_t)3 * E_ * E_;
  float* HN           = (float*)(Pbf + (size_t)3 * BS_ * E_);        // 3*BS*16 fp32
  float* lamRow       = HN + (size_t)3 * BS_ * H_;
  float* znA          = lamRow + 3 * BS_;
  float* chA          = znA + 3 * E_;
  float* shA          = chA + 3 * E_;
  float* out          = (float*)d_out;

  double lb1 = lgamma(E_ / 2.0) + lgamma(0.5) - lgamma(E_ / 2.0 + 0.5);
  double lb2 = lgamma(D_ / 2.0) + lgamma(0.5) - lgamma(D_ / 2.0 + 0.5);
  float scale = (float)exp(lb1 - lb2);

  hipLaunchKernelGGL(row_lam_kernel, dim3(3 * BS_ / 4), dim3(256), 0, stream, q, k, v, lamRow);
  hipLaunchKernelGGL(col_stats_kernel, dim3(48), dim3(256), 0, stream,
                     zq, zk, zv, bq, bk, bv, znA, chA, shA);
  hipLaunchKernelGGL(zsplit_kernel, dim3(16, 16, 3), dim3(256), 0, stream, zq, zk, zv, BhiT, BloT);
  hipLaunchKernelGGL(hlinear_mfma_kernel, dim3(8, 32, 3), dim3(256), 0, stream,
                     q, k, v, BhiT, BloT, lamRow, znA, chA, shA, Wbf);
  hipLaunchKernelGGL(normalize_kernel, dim3(3 * BS_), dim3(256), 0, stream, Wbf, Pbf, HN);
  hipLaunchKernelGGL(attention_kernel, dim3(S_ / 128, H_, B_), dim3(512), 0, stream, Pbf, HN, out, scale);
  hipLaunchKernelGGL(expmap_kernel, dim3(BS_), dim3(256), 0, stream, out);
}

// Round 6
// 438.540 us; speedup vs baseline: 1.0641x; 1.0641x over previous
//
#include <hip/hip_runtime.h>
#include <cmath>

#define EPSF 1e-7f

constexpr int B_ = 4, S_ = 1024, E_ = 1024, H_ = 16, D_ = 64;
constexpr int BS_ = B_ * S_;   // 4096 rows per matrix

typedef __attribute__((ext_vector_type(8))) short bf16x8;
typedef __attribute__((ext_vector_type(4))) float f32x4;

__device__ inline unsigned int fbits(float f) { union { float f; unsigned int u; } x; x.f = f; return x.u; }
__device__ inline float ubits(unsigned int u) { union { unsigned int u; float f; } x; x.u = u; return x.f; }

__device__ inline unsigned short f2bf(float f) {
  unsigned int u = fbits(f);
  unsigned int r = u + 0x7fffu + ((u >> 16) & 1u);   // RNE
  return (unsigned short)(r >> 16);
}
__device__ inline float bf2f(unsigned short h) { return ubits(((unsigned int)h) << 16); }
__device__ inline float fastrcp(float x) { return __builtin_amdgcn_rcpf(x); }

__device__ inline unsigned int packhi(float a, float b) {
  return (fbits(a) >> 16) | (fbits(b) & 0xFFFF0000u);
}
__device__ inline unsigned int packlo(float a, float b) {
  float la = a - ubits(fbits(a) & 0xFFFF0000u);
  float lb = b - ubits(fbits(b) & 0xFFFF0000u);
  return (fbits(la) >> 16) | (fbits(lb) & 0xFFFF0000u);
}

// ---------------- kernel 1: per-row lambda of the three inputs ----------------
__global__ __launch_bounds__(256) void row_lam_kernel(
    const float* __restrict__ xq, const float* __restrict__ xk,
    const float* __restrict__ xv, float* __restrict__ lamRow) {
  int row = blockIdx.x * 4 + (threadIdx.x >> 6);
  int lane = threadIdx.x & 63;
  const float* x = (row < BS_) ? xq : (row < 2 * BS_ ? xk : xv);
  int r = row & (BS_ - 1);
  const float4* xr = (const float4*)(x + (size_t)r * E_);
  float s = 0.f;
  #pragma unroll
  for (int i = 0; i < 4; i++) {
    float4 t = xr[lane + i * 64];
    s += t.x * t.x + t.y * t.y + t.z * t.z + t.w * t.w;
  }
  #pragma unroll
  for (int m = 1; m < 64; m <<= 1) s += __shfl_xor(s, m, 64);
  if (lane == 0) lamRow[row] = 2.0f / fmaxf(1.0f - s, EPSF);
}

// ---------------- kernel 2: column norms of z, cosh/sinh of 2*bias ----------------
__global__ __launch_bounds__(256) void col_stats_kernel(
    const float* __restrict__ zq, const float* __restrict__ zk, const float* __restrict__ zv,
    const float* __restrict__ bq, const float* __restrict__ bk, const float* __restrict__ bv,
    float* __restrict__ znA, float* __restrict__ chA, float* __restrict__ shA) {
  int mat = blockIdx.x >> 4;
  int c0 = (blockIdx.x & 15) * 64;
  const float* z = mat == 0 ? zq : (mat == 1 ? zk : zv);
  const float* bb = mat == 0 ? bq : (mat == 1 ? bk : bv);
  int col = c0 + (threadIdx.x & 63);
  int r0 = threadIdx.x >> 6;
  float s = 0.f;
  for (int rr = r0; rr < E_; rr += 4) {
    float t = z[(size_t)rr * E_ + col];
    s += t * t;
  }
  __shared__ float red[4][64];
  red[r0][threadIdx.x & 63] = s;
  __syncthreads();
  if (r0 == 0) {
    int l = threadIdx.x;
    s = red[0][l] + red[1][l] + red[2][l] + red[3][l];
    float n = fmaxf(sqrtf(s), 1e-15f);
    int idx = mat * E_ + col;
    znA[idx] = n;
    float rb = bb[col];
    chA[idx] = coshf(2.f * rb);
    shA[idx] = sinhf(2.f * rb);
  }
}

// ---------------- kernel 2b: transpose + hi/lo split of z -> BT[n][k] bf16 ----------------
__global__ __launch_bounds__(256) void zsplit_kernel(
    const float* __restrict__ zq, const float* __restrict__ zk, const float* __restrict__ zv,
    unsigned short* __restrict__ BhiT, unsigned short* __restrict__ BloT) {
  const int mat = blockIdx.z;
  const float* z = mat == 0 ? zq : (mat == 1 ? zk : zv);
  const int k0 = blockIdx.y * 64, n0 = blockIdx.x * 64;
  __shared__ float t[64][65];
  const int tid = threadIdx.x;
  {
    int kr = tid >> 4, nc = (tid & 15) * 4;
    #pragma unroll
    for (int i = 0; i < 4; i++) {
      float4 vv = *(const float4*)(z + (size_t)(k0 + kr + i * 16) * E_ + n0 + nc);
      t[kr + i * 16][nc + 0] = vv.x;
      t[kr + i * 16][nc + 1] = vv.y;
      t[kr + i * 16][nc + 2] = vv.z;
      t[kr + i * 16][nc + 3] = vv.w;
    }
  }
  __syncthreads();
  int nr = tid >> 2, kc = (tid & 3) * 16;
  unsigned int ph[8], pl[8];
  #pragma unroll
  for (int p = 0; p < 8; p++) {
    float x0 = t[kc + 2 * p][nr], x1 = t[kc + 2 * p + 1][nr];
    ph[p] = packhi(x0, x1);
    pl[p] = packlo(x0, x1);
  }
  size_t off = (size_t)mat * E_ * E_ + (size_t)(n0 + nr) * E_ + k0 + kc;
  uint4* dh = (uint4*)(BhiT + off);
  uint4* dl = (uint4*)(BloT + off);
  dh[0] = make_uint4(ph[0], ph[1], ph[2], ph[3]);
  dh[1] = make_uint4(ph[4], ph[5], ph[6], ph[7]);
  dl[0] = make_uint4(pl[0], pl[1], pl[2], pl[3]);
  dl[1] = make_uint4(pl[4], pl[5], pl[6], pl[7]);
}

// ---------------- kernel 3: split-bf16 MFMA GEMM, fragment-major LDS, coalesced epilogue ----------------
// LDS tiles stored fragment-major: short offset (row*4 + kchunk)*8. Staging writes land at
// tid*32B contiguous (2-way, free); fragment reads are a lane-bijection of 1KB (conflict-free).
__global__ __launch_bounds__(256, 3) void hlinear_mfma_kernel(
    const float* __restrict__ xq, const float* __restrict__ xk, const float* __restrict__ xv,
    const unsigned short* __restrict__ BhiT, const unsigned short* __restrict__ BloT,
    const float* __restrict__ lamRow, const float* __restrict__ znA,
    const float* __restrict__ chA, const float* __restrict__ shA,
    unsigned short* __restrict__ Wbf) {
  const int mat = blockIdx.z;
  const float* x = mat == 0 ? xq : (mat == 1 ? xk : xv);
  const unsigned short* bh = BhiT + (size_t)mat * E_ * E_;
  const unsigned short* bl = BloT + (size_t)mat * E_ * E_;
  const int lid = blockIdx.y * 8 + blockIdx.x;   // grid (8, 32, 3)
  const int sqi = lid >> 4, offb = lid & 15;
  const int m0 = ((sqi >> 1) * 4 + (offb & 3)) * 128;
  const int n0 = ((sqi & 1) * 4 + (offb >> 2)) * 128;

  // 36864 B: staging = 4 streams x 4096 shorts; epilogue reuses all of it (per-wave 64x72)
  __shared__ unsigned short LDSU[18432];
  unsigned short* Ah = LDSU;
  unsigned short* Al = LDSU + 4096;
  unsigned short* Bh = LDSU + 8192;
  unsigned short* Bl = LDSU + 12288;

  const int tid = threadIdx.x;
  const int wid = tid >> 6, lane = tid & 63, quad = lane >> 4, l16 = lane & 15;
  const int wm = (wid >> 1) * 64, wn = (wid & 1) * 64;

  f32x4 acc[4][4];
  #pragma unroll
  for (int i = 0; i < 4; i++)
    #pragma unroll
    for (int j = 0; j < 4; j++) acc[i][j] = (f32x4){0.f, 0.f, 0.f, 0.f};

  const int arow = tid >> 1;          // tile row 0..127
  const int koff = (tid & 1) * 16;    // element offset in 32-k tile
  const float* aptr = x + (size_t)(m0 + arow) * E_ + koff;
  const unsigned short* bhptr = bh + (size_t)(n0 + arow) * E_ + koff;
  const unsigned short* blptr = bl + (size_t)(n0 + arow) * E_ + koff;
  const int sbase = tid * 16;         // staging write offset (shorts): tid*32 B contiguous

  float4 Ar[4];
  uint4 Brh[2], Brl[2];
  #pragma unroll
  for (int i = 0; i < 4; i++) Ar[i] = *(const float4*)(aptr + i * 4);
  Brh[0] = *(const uint4*)(bhptr);     Brh[1] = *(const uint4*)(bhptr + 8);
  Brl[0] = *(const uint4*)(blptr);     Brl[1] = *(const uint4*)(blptr + 8);

  for (int kt = 0; kt < E_ / 32; ++kt) {
    __syncthreads();
    unsigned int uh[8], ul[8];
    #pragma unroll
    for (int i = 0; i < 4; i++) {
      float4 f = Ar[i];
      uh[2 * i] = packhi(f.x, f.y); uh[2 * i + 1] = packhi(f.z, f.w);
      ul[2 * i] = packlo(f.x, f.y); ul[2 * i + 1] = packlo(f.z, f.w);
    }
    *(uint4*)&Ah[sbase]     = make_uint4(uh[0], uh[1], uh[2], uh[3]);
    *(uint4*)&Ah[sbase + 8] = make_uint4(uh[4], uh[5], uh[6], uh[7]);
    *(uint4*)&Al[sbase]     = make_uint4(ul[0], ul[1], ul[2], ul[3]);
    *(uint4*)&Al[sbase + 8] = make_uint4(ul[4], ul[5], ul[6], ul[7]);
    *(uint4*)&Bh[sbase]     = Brh[0];
    *(uint4*)&Bh[sbase + 8] = Brh[1];
    *(uint4*)&Bl[sbase]     = Brl[0];
    *(uint4*)&Bl[sbase + 8] = Brl[1];
    if (kt < E_ / 32 - 1) {
      int k0 = (kt + 1) * 32;
      #pragma unroll
      for (int i = 0; i < 4; i++) Ar[i] = *(const float4*)(aptr + k0 + i * 4);
      Brh[0] = *(const uint4*)(bhptr + k0);     Brh[1] = *(const uint4*)(bhptr + k0 + 8);
      Brl[0] = *(const uint4*)(blptr + k0);     Brl[1] = *(const uint4*)(blptr + k0 + 8);
    }
    __syncthreads();
    // fragment reads: short offset (row*4 + quad)*8 = row*32 + quad*8
    bf16x8 ah[4], al[4];
    #pragma unroll
    for (int mt = 0; mt < 4; mt++) {
      int ro = (wm + mt * 16 + l16) * 32 + quad * 8;
      ah[mt] = *(const bf16x8*)&Ah[ro];
      al[mt] = *(const bf16x8*)&Al[ro];
    }
    #pragma unroll
    for (int nt = 0; nt < 4; nt++) {
      int ro = (wn + nt * 16 + l16) * 32 + quad * 8;
      bf16x8 bhf = *(const bf16x8*)&Bh[ro];
      bf16x8 blf = *(const bf16x8*)&Bl[ro];
      #pragma unroll
      for (int mt = 0; mt < 4; mt++) {
        acc[mt][nt] = __builtin_amdgcn_mfma_f32_16x16x32_bf16(ah[mt], bhf, acc[mt][nt], 0, 0, 0);
        acc[mt][nt] = __builtin_amdgcn_mfma_f32_16x16x32_bf16(ah[mt], blf, acc[mt][nt], 0, 0, 0);
        acc[mt][nt] = __builtin_amdgcn_mfma_f32_16x16x32_bf16(al[mt], bhf, acc[mt][nt], 0, 0, 0);
      }
    }
  }

  // ---- epilogue: compute w, stage per-wave 64x64 bf16 subtile in LDS, copy out coalesced ----
  const float* lamP = lamRow + mat * BS_;
  float lamv[16];
  #pragma unroll
  for (int mt = 0; mt < 4; mt++)
    #pragma unroll
    for (int r = 0; r < 4; r++)
      lamv[mt * 4 + r] = lamP[m0 + wm + mt * 16 + quad * 4 + r];

  __syncthreads();   // all waves done reading staging LDS; safe to reuse for epilogue
  unsigned short* epi = LDSU + wid * 4608;   // 64 rows x 72 shorts (144 B stride)
  #pragma unroll
  for (int nt = 0; nt < 4; nt++) {
    int cg = n0 + wn + nt * 16 + l16;
    float zn = znA[mat * E_ + cg];
    float chzn = chA[mat * E_ + cg] / zn;
    float sh = shA[mat * E_ + cg];
    float tzn = 2.f * zn;
    #pragma unroll
    for (int mt = 0; mt < 4; mt++) {
      #pragma unroll
      for (int r = 0; r < 4; r++) {
        float lam = lamv[mt * 4 + r];
        float arg = fmaf(lam * acc[mt][nt][r], chzn, -(lam - 1.f) * sh);
        float sq2 = sqrtf(fmaf(arg, arg, 1.f));
        float v = tzn * __logf(arg + sq2);
        float ev = __expf(v);
        float w = 0.5f * (ev - fastrcp(ev));
        epi[(mt * 16 + quad * 4 + r) * 72 + nt * 16 + l16] = f2bf(w);
      }
    }
  }
  // wave-private region: no barrier needed (compiler orders ds write->read via lgkmcnt)
  unsigned short* gout = Wbf + (size_t)mat * BS_ * E_ + (size_t)(m0 + wm) * E_ + n0 + wn;
  const int rrow = lane >> 3, seg = lane & 7;
  #pragma unroll
  for (int i = 0; i < 8; i++) {
    int row = i * 8 + rrow;
    uint4 val = *(const uint4*)&epi[row * 72 + seg * 8];
    *(uint4*)(gout + (size_t)row * E_ + seg * 8) = val;
  }
}

// ---------------- kernel 4: normalize bf16 w -> bf16 P + per-head squared norms ----------------
__global__ __launch_bounds__(256) void normalize_kernel(
    const unsigned short* __restrict__ Wbf, unsigned short* __restrict__ Pbf,
    float* __restrict__ HN) {
  const unsigned short* w = Wbf + (size_t)blockIdx.x * E_;
  int tid = threadIdx.x;
  uint2 wv = ((const uint2*)w)[tid];   // 4 bf16
  float w0 = bf2f((unsigned short)(wv.x & 0xFFFF));
  float w1 = bf2f((unsigned short)(wv.x >> 16));
  float w2 = bf2f((unsigned short)(wv.y & 0xFFFF));
  float w3 = bf2f((unsigned short)(wv.y >> 16));
  float s = w0 * w0 + w1 * w1 + w2 * w2 + w3 * w3;
  #pragma unroll
  for (int m = 1; m < 64; m <<= 1) s += __shfl_xor(s, m, 64);
  __shared__ float red[4];
  if ((tid & 63) == 0) red[tid >> 6] = s;
  __syncthreads();
  s = red[0] + red[1] + red[2] + red[3];
  float t = 1.f / (1.f + sqrtf(1.f + s));
  unsigned short p0 = f2bf(w0 * t), p1 = f2bf(w1 * t), p2 = f2bf(w2 * t), p3 = f2bf(w3 * t);
  uint2 pk;
  pk.x = (unsigned int)p0 | ((unsigned int)p1 << 16);
  pk.y = (unsigned int)p2 | ((unsigned int)p3 << 16);
  ((uint2*)(Pbf + (size_t)blockIdx.x * E_))[tid] = pk;
  float r0 = bf2f(p0), r1 = bf2f(p1), r2 = bf2f(p2), r3 = bf2f(p3);
  float hs = r0 * r0 + r1 * r1 + r2 * r2 + r3 * r3;
  hs += __shfl_xor(hs, 1, 64);
  hs += __shfl_xor(hs, 2, 64);
  hs += __shfl_xor(hs, 4, 64);
  hs += __shfl_xor(hs, 8, 64);
  if ((tid & 15) == 0) HN[(size_t)blockIdx.x * H_ + (tid >> 4)] = hs;
}

// ---------------- kernel 5: MFMA flash hyperbolic attention ----------------
__global__ __launch_bounds__(512) void attention_kernel(
    const unsigned short* __restrict__ Pbf, const float* __restrict__ HN,
    float* __restrict__ TV, float scale) {
  const int qt = blockIdx.x, h = blockIdx.y, b = blockIdx.z;
  const unsigned short* pq = Pbf;
  const unsigned short* pk = Pbf + (size_t)BS_ * E_;
  const unsigned short* pv = Pbf + (size_t)2 * BS_ * E_;
  const float* hnq = HN;
  const float* hnk = HN + (size_t)BS_ * H_;
  const float* hnv = HN + (size_t)2 * BS_ * H_;

  const int tid = threadIdx.x;
  const int wid = tid >> 6, lane = tid & 63;
  const int quad = lane >> 4, l16 = lane & 15;

  __shared__ unsigned short Kbf[64][72];
  __shared__ unsigned short Vt[64][72];
  __shared__ unsigned short Pw[8][16][72];
  __shared__ float k2s[64], romk2s[64], lamLs[64];

  const int qrow0 = qt * 128 + wid * 16;
  const size_t qgrow = ((size_t)(b * S_ + qrow0 + l16)) * E_ + h * 64;
  bf16x8 aq0 = *(const bf16x8*)(pq + qgrow + quad * 8);
  bf16x8 aq1 = *(const bf16x8*)(pq + qgrow + 32 + quad * 8);
  float q2r[4], tromq2[4];
  #pragma unroll
  for (int r2 = 0; r2 < 4; r2++) {
    float q2 = hnq[((size_t)(b * S_ + qrow0 + quad * 4 + r2)) * H_ + h];
    q2r[r2] = q2;
    tromq2[r2] = 2.f * fastrcp(1.f - q2);
  }

  float aWL[4] = {0.f, 0.f, 0.f, 0.f};
  float aW[4]  = {0.f, 0.f, 0.f, 0.f};
  f32x4 accO[4];
  #pragma unroll
  for (int dt = 0; dt < 4; dt++) accO[dt] = (f32x4){0.f, 0.f, 0.f, 0.f};

  for (int kt = 0; kt < S_ / 64; ++kt) {
    __syncthreads();
    {
      int row = tid >> 3, col = (tid & 7) * 8;
      const uint4* src = (const uint4*)(pk + ((size_t)(b * S_ + kt * 64 + row)) * E_ + h * 64 + col);
      *(uint4*)&Kbf[row][col] = *src;
    }
    if (tid < 64) {
      float k2 = hnk[((size_t)(b * S_ + kt * 64 + tid)) * H_ + h];
      k2s[tid] = k2;
      romk2s[tid] = fastrcp(1.f - k2);
      float v2 = hnv[((size_t)(b * S_ + kt * 64 + tid)) * H_ + h];
      lamLs[tid] = 2.f / fmaxf(1.f - v2, EPSF);
    }
    {
      int key = tid & 63, dg = tid >> 6;
      union { uint4 q; unsigned short u[8]; } vv;
      vv.q = *(const uint4*)(pv + ((size_t)(b * S_ + kt * 64 + key)) * E_ + h * 64 + dg * 8);
      #pragma unroll
      for (int d = 0; d < 8; d++)
        Vt[dg * 8 + d][key] = vv.u[d];
    }
    __syncthreads();

    #pragma unroll
    for (int nt = 0; nt < 4; nt++) {
      bf16x8 bk0 = *(const bf16x8*)&Kbf[nt * 16 + l16][quad * 8];
      bf16x8 bk1 = *(const bf16x8*)&Kbf[nt * 16 + l16][32 + quad * 8];
      f32x4 z = (f32x4){0.f, 0.f, 0.f, 0.f};
      f32x4 d0 = __builtin_amdgcn_mfma_f32_16x16x32_bf16(aq0, bk0, z, 0, 0, 0);
      d0 = __builtin_amdgcn_mfma_f32_16x16x32_bf16(aq1, bk1, d0, 0, 0, 0);
      float k2 = k2s[nt * 16 + l16];
      float romk2 = romk2s[nt * 16 + l16];
      float lamL = lamLs[nt * 16 + l16];
      #pragma unroll
      for (int r2 = 0; r2 < 4; r2++) {
        float diff2 = fmaf(-2.f, d0[r2], q2r[r2] + k2);
        float t = fmaxf(diff2 * (tromq2[r2] * romk2), 1e-6f);
        float w = fastrcp((1.f + t) + sqrtf(fmaf(t, t, t + t)));
        float wl = w * lamL;
        Pw[wid][quad * 4 + r2][nt * 16 + l16] = f2bf(wl);
        aWL[r2] += wl;
        aW[r2] += w;
      }
    }
    bf16x8 ap0 = *(const bf16x8*)&Pw[wid][l16][quad * 8];
    bf16x8 ap1 = *(const bf16x8*)&Pw[wid][l16][32 + quad * 8];
    #pragma unroll
    for (int dt = 0; dt < 4; dt++) {
      bf16x8 bv0 = *(const bf16x8*)&Vt[dt * 16 + l16][quad * 8];
      bf16x8 bv1 = *(const bf16x8*)&Vt[dt * 16 + l16][32 + quad * 8];
      accO[dt] = __builtin_amdgcn_mfma_f32_16x16x32_bf16(ap0, bv0, accO[dt], 0, 0, 0);
      accO[dt] = __builtin_amdgcn_mfma_f32_16x16x32_bf16(ap1, bv1, accO[dt], 0, 0, 0);
    }
  }

  #pragma unroll
  for (int r2 = 0; r2 < 4; r2++) {
    float dsum = aWL[r2] - aW[r2];
    dsum += __shfl_xor(dsum, 1, 64);
    dsum += __shfl_xor(dsum, 2, 64);
    dsum += __shfl_xor(dsum, 4, 64);
    dsum += __shfl_xor(dsum, 8, 64);
    float uu[4];
    float su = 0.f;
    #pragma unroll
    for (int dt = 0; dt < 4; dt++) { uu[dt] = accO[dt][r2] / dsum; su += uu[dt] * uu[dt]; }
    su += __shfl_xor(su, 1, 64);
    su += __shfl_xor(su, 2, 64);
    su += __shfl_xor(su, 4, 64);
    su += __shfl_xor(su, 8, 64);
    float g = 1.f / (1.f + sqrtf(fmaxf(1.f - su, EPSF)));
    float n2 = fmaxf(su * g * g, 1e-15f);
    float n = sqrtf(n2);
    float fac = atanhf(fminf(n, 1.f - 1e-6f)) / n * g * scale;
    size_t orow = ((size_t)(b * S_ + qrow0 + quad * 4 + r2)) * E_ + h * 64 + l16;
    #pragma unroll
    for (int dt = 0; dt < 4; dt++) TV[orow + dt * 16] = fac * uu[dt];
  }
}

// ---------------- kernel 6: expmap0 per full E-row, in-place on d_out ----------------
__global__ __launch_bounds__(256) void expmap_kernel(float* __restrict__ TV) {
  float* w = TV + (size_t)blockIdx.x * E_;
  int tid = threadIdx.x;
  float4 v = ((float4*)w)[tid];
  float s = v.x * v.x + v.y * v.y + v.z * v.z + v.w * v.w;
  #pragma unroll
  for (int m = 1; m < 64; m <<= 1) s += __shfl_xor(s, m, 64);
  __shared__ float red[4];
  if ((tid & 63) == 0) red[tid >> 6] = s;
  __syncthreads();
  s = red[0] + red[1] + red[2] + red[3];
  float n = sqrtf(fmaxf(s, 1e-15f));
  float f = tanhf(n) / n;
  v.x *= f; v.y *= f; v.z *= f; v.w *= f;
  ((float4*)w)[tid] = v;
}

extern "C" void kernel_launch(void* const* d_in, const int* in_sizes, int n_in,
                              void* d_out, int out_size, void* d_ws, size_t ws_size,
                              hipStream_t stream) {
  (void)in_sizes; (void)n_in; (void)out_size; (void)ws_size;
  const float* q  = (const float*)d_in[0];
  const float* k  = (const float*)d_in[1];
  const float* v  = (const float*)d_in[2];
  const float* zq = (const float*)d_in[3];
  const float* bq = (const float*)d_in[4];
  const float* zk = (const float*)d_in[5];
  const float* bk = (const float*)d_in[6];
  const float* zv = (const float*)d_in[7];
  const float* bv = (const float*)d_in[8];

  unsigned short* Wbf = (unsigned short*)d_ws;                       // 3*BS*E bf16 (25.2 MB)
  unsigned short* Pbf = Wbf + (size_t)3 * BS_ * E_;                  // 3*BS*E bf16 (25.2 MB)
  unsigned short* BhiT = Pbf;                                        // aliases Pbf (dead until normalize)
  unsigned short* BloT = Pbf + (size_t)3 * E_ * E_;
  float* HN           = (float*)(Pbf + (size_t)3 * BS_ * E_);        // 3*BS*16 fp32
  float* lamRow       = HN + (size_t)3 * BS_ * H_;
  float* znA          = lamRow + 3 * BS_;
  float* chA          = znA + 3 * E_;
  float* shA          = chA + 3 * E_;
  float* out          = (float*)d_out;

  double lb1 = lgamma(E_ / 2.0) + lgamma(0.5) - lgamma(E_ / 2.0 + 0.5);
  double lb2 = lgamma(D_ / 2.0) + lgamma(0.5) - lgamma(D_ / 2.0 + 0.5);
  float scale = (float)exp(lb1 - lb2);

  hipLaunchKernelGGL(row_lam_kernel, dim3(3 * BS_ / 4), dim3(256), 0, stream, q, k, v, lamRow);
  hipLaunchKernelGGL(col_stats_kernel, dim3(48), dim3(256), 0, stream,
                     zq, zk, zv, bq, bk, bv, znA, chA, shA);
  hipLaunchKernelGGL(zsplit_kernel, dim3(16, 16, 3), dim3(256), 0, stream, zq, zk, zv, BhiT, BloT);
  hipLaunchKernelGGL(hlinear_mfma_kernel, dim3(8, 32, 3), dim3(256), 0, stream,
                     q, k, v, BhiT, BloT, lamRow, znA, chA, shA, Wbf);
  hipLaunchKernelGGL(normalize_kernel, dim3(3 * BS_), dim3(256), 0, stream, Wbf, Pbf, HN);
  hipLaunchKernelGGL(attention_kernel, dim3(S_ / 128, H_, B_), dim3(512), 0, stream, Pbf, HN, out, scale);
  hipLaunchKernelGGL(expmap_kernel, dim3(BS_), dim3(256), 0, stream, out);
}

// Round 7
// 394.418 us; speedup vs baseline: 1.1831x; 1.1119x over previous
//
#include <hip/hip_runtime.h>
#include <cmath>

#define EPSF 1e-7f

constexpr int B_ = 4, S_ = 1024, E_ = 1024, H_ = 16, D_ = 64;
constexpr int BS_ = B_ * S_;   // 4096 rows per matrix

typedef __attribute__((ext_vector_type(8))) short bf16x8;
typedef __attribute__((ext_vector_type(4))) float f32x4;

__device__ inline unsigned int fbits(float f) { union { float f; unsigned int u; } x; x.f = f; return x.u; }
__device__ inline float ubits(unsigned int u) { union { unsigned int u; float f; } x; x.u = u; return x.f; }

__device__ inline unsigned short f2bf(float f) {
  unsigned int u = fbits(f);
  unsigned int r = u + 0x7fffu + ((u >> 16) & 1u);   // RNE
  return (unsigned short)(r >> 16);
}
__device__ inline float bf2f(unsigned short h) { return ubits(((unsigned int)h) << 16); }
__device__ inline float fastrcp(float x) { return __builtin_amdgcn_rcpf(x); }

__device__ inline unsigned int packhi(float a, float b) {
  return (fbits(a) >> 16) | (fbits(b) & 0xFFFF0000u);
}
__device__ inline unsigned int packlo(float a, float b) {
  float la = a - ubits(fbits(a) & 0xFFFF0000u);
  float lb = b - ubits(fbits(b) & 0xFFFF0000u);
  return (fbits(la) >> 16) | (fbits(lb) & 0xFFFF0000u);
}

// async global -> LDS DMA, 16B per lane; LDS dest = wave-uniform base + lane*16
__device__ __forceinline__ void async_ld16(const unsigned short* g, unsigned short* l) {
  __builtin_amdgcn_global_load_lds(
      (const __attribute__((address_space(1))) unsigned int*)g,
      (__attribute__((address_space(3))) unsigned int*)l, 16, 0, 0);
}

// ---------------- kernel 1: x -> RNE bf16 + per-row lambda (fused) ----------------
__global__ __launch_bounds__(256) void xsplit_kernel(
    const float* __restrict__ xq, const float* __restrict__ xk,
    const float* __restrict__ xv, unsigned short* __restrict__ Xbf,
    float* __restrict__ lamRow) {
  const int row = blockIdx.x;                 // 0 .. 3*BS-1
  const float* x = (row < BS_) ? xq : (row < 2 * BS_ ? xk : xv);
  const int r = row & (BS_ - 1);
  const int tid = threadIdx.x;
  float4 v = ((const float4*)(x + (size_t)r * E_))[tid];
  float s = v.x * v.x + v.y * v.y + v.z * v.z + v.w * v.w;
  #pragma unroll
  for (int m = 1; m < 64; m <<= 1) s += __shfl_xor(s, m, 64);
  __shared__ float red[4];
  if ((tid & 63) == 0) red[tid >> 6] = s;
  __syncthreads();
  s = red[0] + red[1] + red[2] + red[3];
  uint2 p;
  p.x = (unsigned int)f2bf(v.x) | ((unsigned int)f2bf(v.y) << 16);
  p.y = (unsigned int)f2bf(v.z) | ((unsigned int)f2bf(v.w) << 16);
  ((uint2*)(Xbf + (size_t)row * E_))[tid] = p;
  if (tid == 0) lamRow[row] = 2.0f / fmaxf(1.0f - s, EPSF);
}

// ---------------- kernel 2: column norms of z, cosh/sinh of 2*bias ----------------
__global__ __launch_bounds__(256) void col_stats_kernel(
    const float* __restrict__ zq, const float* __restrict__ zk, const float* __restrict__ zv,
    const float* __restrict__ bq, const float* __restrict__ bk, const float* __restrict__ bv,
    float* __restrict__ znA, float* __restrict__ chA, float* __restrict__ shA) {
  int mat = blockIdx.x >> 4;
  int c0 = (blockIdx.x & 15) * 64;
  const float* z = mat == 0 ? zq : (mat == 1 ? zk : zv);
  const float* bb = mat == 0 ? bq : (mat == 1 ? bk : bv);
  int col = c0 + (threadIdx.x & 63);
  int r0 = threadIdx.x >> 6;
  float s = 0.f;
  for (int rr = r0; rr < E_; rr += 4) {
    float t = z[(size_t)rr * E_ + col];
    s += t * t;
  }
  __shared__ float red[4][64];
  red[r0][threadIdx.x & 63] = s;
  __syncthreads();
  if (r0 == 0) {
    int l = threadIdx.x;
    s = red[0][l] + red[1][l] + red[2][l] + red[3][l];
    float n = fmaxf(sqrtf(s), 1e-15f);
    int idx = mat * E_ + col;
    znA[idx] = n;
    float rb = bb[col];
    chA[idx] = coshf(2.f * rb);
    shA[idx] = sinhf(2.f * rb);
  }
}

// ---------------- kernel 2b: transpose + hi/lo split of z -> BT[n][k] bf16 ----------------
__global__ __launch_bounds__(256) void zsplit_kernel(
    const float* __restrict__ zq, const float* __restrict__ zk, const float* __restrict__ zv,
    unsigned short* __restrict__ BhiT, unsigned short* __restrict__ BloT) {
  const int mat = blockIdx.z;
  const float* z = mat == 0 ? zq : (mat == 1 ? zk : zv);
  const int k0 = blockIdx.y * 64, n0 = blockIdx.x * 64;
  __shared__ float t[64][65];
  const int tid = threadIdx.x;
  {
    int kr = tid >> 4, nc = (tid & 15) * 4;
    #pragma unroll
    for (int i = 0; i < 4; i++) {
      float4 vv = *(const float4*)(z + (size_t)(k0 + kr + i * 16) * E_ + n0 + nc);
      t[kr + i * 16][nc + 0] = vv.x;
      t[kr + i * 16][nc + 1] = vv.y;
      t[kr + i * 16][nc + 2] = vv.z;
      t[kr + i * 16][nc + 3] = vv.w;
    }
  }
  __syncthreads();
  int nr = tid >> 2, kc = (tid & 3) * 16;
  unsigned int ph[8], pl[8];
  #pragma unroll
  for (int p = 0; p < 8; p++) {
    float x0 = t[kc + 2 * p][nr], x1 = t[kc + 2 * p + 1][nr];
    ph[p] = packhi(x0, x1);
    pl[p] = packlo(x0, x1);
  }
  size_t off = (size_t)mat * E_ * E_ + (size_t)(n0 + nr) * E_ + k0 + kc;
  uint4* dh = (uint4*)(BhiT + off);
  uint4* dl = (uint4*)(BloT + off);
  dh[0] = make_uint4(ph[0], ph[1], ph[2], ph[3]);
  dh[1] = make_uint4(ph[4], ph[5], ph[6], ph[7]);
  dl[0] = make_uint4(pl[0], pl[1], pl[2], pl[3]);
  dl[1] = make_uint4(pl[4], pl[5], pl[6], pl[7]);
}

// ---------------- kernel 3: 2-term bf16 MFMA GEMM (A*Bhi + A*Blo), async DMA staging ----------------
// BK=64, 3 streams via global_load_lds(16B). XOR column swizzle: global lane col
// (lane&7)^(row&7) keeps 128B-line coalescing AND makes frag ds_read_b128 bank-uniform.
__global__ __launch_bounds__(256, 3) void hlinear_mfma_kernel(
    const unsigned short* __restrict__ Xbf,
    const unsigned short* __restrict__ BhiT, const unsigned short* __restrict__ BloT,
    const float* __restrict__ lamRow, const float* __restrict__ znA,
    const float* __restrict__ chA, const float* __restrict__ shA,
    unsigned short* __restrict__ Wbf) {
  const int mat = blockIdx.z;
  const unsigned short* xa = Xbf + (size_t)mat * BS_ * E_;
  const unsigned short* bh = BhiT + (size_t)mat * E_ * E_;
  const unsigned short* bl = BloT + (size_t)mat * E_ * E_;
  const int lid = blockIdx.y * 8 + blockIdx.x;   // grid (8, 32, 3)
  const int sqi = lid >> 4, offb = lid & 15;
  const int m0 = ((sqi >> 1) * 4 + (offb & 3)) * 128;
  const int n0 = ((sqi & 1) * 4 + (offb >> 2)) * 128;

  __shared__ unsigned short LDSU[24576];   // 49152 B; epilogue reuses it
  unsigned short* As = LDSU;               // 128 rows x 64 shorts
  unsigned short* Bh = LDSU + 8192;
  unsigned short* Bl = LDSU + 16384;

  const int tid = threadIdx.x;
  const int wid = tid >> 6, lane = tid & 63, quad = lane >> 4, l16 = lane & 15;
  const int wm = (wid >> 1) * 64, wn = (wid & 1) * 64;

  f32x4 acc[4][4];
  #pragma unroll
  for (int i = 0; i < 4; i++)
    #pragma unroll
    for (int j = 0; j < 4; j++) acc[i][j] = (f32x4){0.f, 0.f, 0.f, 0.f};

  const int lrow = lane >> 3;                       // 0..7 within chunk
  const int lcs = ((lane & 7) ^ lrow) * 8;          // swizzled col (shorts)
  const int xsw = (l16 & 7);                        // row&7 for frag reads

  for (int kt = 0; kt < E_ / 64; ++kt) {
    __syncthreads();
    const int kb = kt * 64 + lcs;
    #pragma unroll
    for (int c2 = 0; c2 < 4; c2++) {
      const int c = wid * 4 + c2;
      const int grow = c * 8 + lrow;
      async_ld16(xa + (size_t)(m0 + grow) * E_ + kb, As + c * 512);
      async_ld16(bh + (size_t)(n0 + grow) * E_ + kb, Bh + c * 512);
      async_ld16(bl + (size_t)(n0 + grow) * E_ + kb, Bl + c * 512);
    }
    __syncthreads();
    #pragma unroll
    for (int h = 0; h < 2; h++) {
      bf16x8 a[4];
      #pragma unroll
      for (int mt = 0; mt < 4; mt++) {
        int row = wm + mt * 16 + l16;
        a[mt] = *(const bf16x8*)&As[row * 64 + (((h * 4 + quad) ^ xsw) * 8)];
      }
      #pragma unroll
      for (int nt = 0; nt < 4; nt++) {
        int row = wn + nt * 16 + l16;
        int ro = row * 64 + (((h * 4 + quad) ^ xsw) * 8);
        bf16x8 bhf = *(const bf16x8*)&Bh[ro];
        bf16x8 blf = *(const bf16x8*)&Bl[ro];
        #pragma unroll
        for (int mt = 0; mt < 4; mt++) {
          acc[mt][nt] = __builtin_amdgcn_mfma_f32_16x16x32_bf16(a[mt], bhf, acc[mt][nt], 0, 0, 0);
          acc[mt][nt] = __builtin_amdgcn_mfma_f32_16x16x32_bf16(a[mt], blf, acc[mt][nt], 0, 0, 0);
        }
      }
    }
  }

  // ---- epilogue: compute w, stage per-wave 64x64 bf16 subtile in LDS, copy out coalesced ----
  const float* lamP = lamRow + mat * BS_;
  float lamv[16];
  #pragma unroll
  for (int mt = 0; mt < 4; mt++)
    #pragma unroll
    for (int r = 0; r < 4; r++)
      lamv[mt * 4 + r] = lamP[m0 + wm + mt * 16 + quad * 4 + r];

  __syncthreads();   // all waves done with staging LDS
  unsigned short* epi = LDSU + wid * 4608;   // 64 rows x 72 shorts
  #pragma unroll
  for (int nt = 0; nt < 4; nt++) {
    int cg = n0 + wn + nt * 16 + l16;
    float zn = znA[mat * E_ + cg];
    float chzn = chA[mat * E_ + cg] / zn;
    float sh = shA[mat * E_ + cg];
    float tzn = 2.f * zn;
    #pragma unroll
    for (int mt = 0; mt < 4; mt++) {
      #pragma unroll
      for (int r = 0; r < 4; r++) {
        float lam = lamv[mt * 4 + r];
        float arg = fmaf(lam * acc[mt][nt][r], chzn, -(lam - 1.f) * sh);
        float sq2 = sqrtf(fmaf(arg, arg, 1.f));
        float v = tzn * __logf(arg + sq2);
        float ev = __expf(v);
        float w = 0.5f * (ev - fastrcp(ev));
        epi[(mt * 16 + quad * 4 + r) * 72 + nt * 16 + l16] = f2bf(w);
      }
    }
  }
  unsigned short* gout = Wbf + (size_t)mat * BS_ * E_ + (size_t)(m0 + wm) * E_ + n0 + wn;
  const int rrow = lane >> 3, seg = lane & 7;
  #pragma unroll
  for (int i = 0; i < 8; i++) {
    int row = i * 8 + rrow;
    uint4 val = *(const uint4*)&epi[row * 72 + seg * 8];
    *(uint4*)(gout + (size_t)row * E_ + seg * 8) = val;
  }
}

// ---------------- kernel 4: normalize bf16 w -> bf16 P + per-head squared norms ----------------
__global__ __launch_bounds__(256) void normalize_kernel(
    const unsigned short* __restrict__ Wbf, unsigned short* __restrict__ Pbf,
    float* __restrict__ HN) {
  const unsigned short* w = Wbf + (size_t)blockIdx.x * E_;
  int tid = threadIdx.x;
  uint2 wv = ((const uint2*)w)[tid];   // 4 bf16
  float w0 = bf2f((unsigned short)(wv.x & 0xFFFF));
  float w1 = bf2f((unsigned short)(wv.x >> 16));
  float w2 = bf2f((unsigned short)(wv.y & 0xFFFF));
  float w3 = bf2f((unsigned short)(wv.y >> 16));
  float s = w0 * w0 + w1 * w1 + w2 * w2 + w3 * w3;
  #pragma unroll
  for (int m = 1; m < 64; m <<= 1) s += __shfl_xor(s, m, 64);
  __shared__ float red[4];
  if ((tid & 63) == 0) red[tid >> 6] = s;
  __syncthreads();
  s = red[0] + red[1] + red[2] + red[3];
  float t = 1.f / (1.f + sqrtf(1.f + s));
  unsigned short p0 = f2bf(w0 * t), p1 = f2bf(w1 * t), p2 = f2bf(w2 * t), p3 = f2bf(w3 * t);
  uint2 pk;
  pk.x = (unsigned int)p0 | ((unsigned int)p1 << 16);
  pk.y = (unsigned int)p2 | ((unsigned int)p3 << 16);
  ((uint2*)(Pbf + (size_t)blockIdx.x * E_))[tid] = pk;
  float r0 = bf2f(p0), r1 = bf2f(p1), r2 = bf2f(p2), r3 = bf2f(p3);
  float hs = r0 * r0 + r1 * r1 + r2 * r2 + r3 * r3;
  hs += __shfl_xor(hs, 1, 64);
  hs += __shfl_xor(hs, 2, 64);
  hs += __shfl_xor(hs, 4, 64);
  hs += __shfl_xor(hs, 8, 64);
  if ((tid & 15) == 0) HN[(size_t)blockIdx.x * H_ + (tid >> 4)] = hs;
}

// ---------------- kernel 5: MFMA flash hyperbolic attention ----------------
__global__ __launch_bounds__(512) void attention_kernel(
    const unsigned short* __restrict__ Pbf, const float* __restrict__ HN,
    float* __restrict__ TV, float scale) {
  const int qt = blockIdx.x, h = blockIdx.y, b = blockIdx.z;
  const unsigned short* pq = Pbf;
  const unsigned short* pk = Pbf + (size_t)BS_ * E_;
  const unsigned short* pv = Pbf + (size_t)2 * BS_ * E_;
  const float* hnq = HN;
  const float* hnk = HN + (size_t)BS_ * H_;
  const float* hnv = HN + (size_t)2 * BS_ * H_;

  const int tid = threadIdx.x;
  const int wid = tid >> 6, lane = tid & 63;
  const int quad = lane >> 4, l16 = lane & 15;

  __shared__ unsigned short Kbf[64][72];
  __shared__ unsigned short Vt[64][72];
  __shared__ unsigned short Pw[8][16][72];
  __shared__ float k2s[64], romk2s[64], lamLs[64];

  const int qrow0 = qt * 128 + wid * 16;
  const size_t qgrow = ((size_t)(b * S_ + qrow0 + l16)) * E_ + h * 64;
  bf16x8 aq0 = *(const bf16x8*)(pq + qgrow + quad * 8);
  bf16x8 aq1 = *(const bf16x8*)(pq + qgrow + 32 + quad * 8);
  float q2r[4], tromq2[4];
  #pragma unroll
  for (int r2 = 0; r2 < 4; r2++) {
    float q2 = hnq[((size_t)(b * S_ + qrow0 + quad * 4 + r2)) * H_ + h];
    q2r[r2] = q2;
    tromq2[r2] = 2.f * fastrcp(1.f - q2);
  }

  float aWL[4] = {0.f, 0.f, 0.f, 0.f};
  float aW[4]  = {0.f, 0.f, 0.f, 0.f};
  f32x4 accO[4];
  #pragma unroll
  for (int dt = 0; dt < 4; dt++) accO[dt] = (f32x4){0.f, 0.f, 0.f, 0.f};

  for (int kt = 0; kt < S_ / 64; ++kt) {
    __syncthreads();
    {
      int row = tid >> 3, col = (tid & 7) * 8;
      const uint4* src = (const uint4*)(pk + ((size_t)(b * S_ + kt * 64 + row)) * E_ + h * 64 + col);
      *(uint4*)&Kbf[row][col] = *src;
    }
    if (tid < 64) {
      float k2 = hnk[((size_t)(b * S_ + kt * 64 + tid)) * H_ + h];
      k2s[tid] = k2;
      romk2s[tid] = fastrcp(1.f - k2);
      float v2 = hnv[((size_t)(b * S_ + kt * 64 + tid)) * H_ + h];
      lamLs[tid] = 2.f / fmaxf(1.f - v2, EPSF);
    }
    {
      int key = tid & 63, dg = tid >> 6;
      union { uint4 q; unsigned short u[8]; } vv;
      vv.q = *(const uint4*)(pv + ((size_t)(b * S_ + kt * 64 + key)) * E_ + h * 64 + dg * 8);
      #pragma unroll
      for (int d = 0; d < 8; d++)
        Vt[dg * 8 + d][key] = vv.u[d];
    }
    __syncthreads();

    #pragma unroll
    for (int nt = 0; nt < 4; nt++) {
      bf16x8 bk0 = *(const bf16x8*)&Kbf[nt * 16 + l16][quad * 8];
      bf16x8 bk1 = *(const bf16x8*)&Kbf[nt * 16 + l16][32 + quad * 8];
      f32x4 z = (f32x4){0.f, 0.f, 0.f, 0.f};
      f32x4 d0 = __builtin_amdgcn_mfma_f32_16x16x32_bf16(aq0, bk0, z, 0, 0, 0);
      d0 = __builtin_amdgcn_mfma_f32_16x16x32_bf16(aq1, bk1, d0, 0, 0, 0);
      float k2 = k2s[nt * 16 + l16];
      float romk2 = romk2s[nt * 16 + l16];
      float lamL = lamLs[nt * 16 + l16];
      #pragma unroll
      for (int r2 = 0; r2 < 4; r2++) {
        float diff2 = fmaf(-2.f, d0[r2], q2r[r2] + k2);
        float t = fmaxf(diff2 * (tromq2[r2] * romk2), 1e-6f);
        float w = fastrcp((1.f + t) + sqrtf(fmaf(t, t, t + t)));
        float wl = w * lamL;
        Pw[wid][quad * 4 + r2][nt * 16 + l16] = f2bf(wl);
        aWL[r2] += wl;
        aW[r2] += w;
      }
    }
    bf16x8 ap0 = *(const bf16x8*)&Pw[wid][l16][quad * 8];
    bf16x8 ap1 = *(const bf16x8*)&Pw[wid][l16][32 + quad * 8];
    #pragma unroll
    for (int dt = 0; dt < 4; dt++) {
      bf16x8 bv0 = *(const bf16x8*)&Vt[dt * 16 + l16][quad * 8];
      bf16x8 bv1 = *(const bf16x8*)&Vt[dt * 16 + l16][32 + quad * 8];
      accO[dt] = __builtin_amdgcn_mfma_f32_16x16x32_bf16(ap0, bv0, accO[dt], 0, 0, 0);
      accO[dt] = __builtin_amdgcn_mfma_f32_16x16x32_bf16(ap1, bv1, accO[dt], 0, 0, 0);
    }
  }

  #pragma unroll
  for (int r2 = 0; r2 < 4; r2++) {
    float dsum = aWL[r2] - aW[r2];
    dsum += __shfl_xor(dsum, 1, 64);
    dsum += __shfl_xor(dsum, 2, 64);
    dsum += __shfl_xor(dsum, 4, 64);
    dsum += __shfl_xor(dsum, 8, 64);
    float uu[4];
    float su = 0.f;
    #pragma unroll
    for (int dt = 0; dt < 4; dt++) { uu[dt] = accO[dt][r2] / dsum; su += uu[dt] * uu[dt]; }
    su += __shfl_xor(su, 1, 64);
    su += __shfl_xor(su, 2, 64);
    su += __shfl_xor(su, 4, 64);
    su += __shfl_xor(su, 8, 64);
    float g = 1.f / (1.f + sqrtf(fmaxf(1.f - su, EPSF)));
    float n2 = fmaxf(su * g * g, 1e-15f);
    float n = sqrtf(n2);
    float fac = atanhf(fminf(n, 1.f - 1e-6f)) / n * g * scale;
    size_t orow = ((size_t)(b * S_ + qrow0 + quad * 4 + r2)) * E_ + h * 64 + l16;
    #pragma unroll
    for (int dt = 0; dt < 4; dt++) TV[orow + dt * 16] = fac * uu[dt];
  }
}

// ---------------- kernel 6: expmap0 per full E-row, in-place on d_out ----------------
__global__ __launch_bounds__(256) void expmap_kernel(float* __restrict__ TV) {
  float* w = TV + (size_t)blockIdx.x * E_;
  int tid = threadIdx.x;
  float4 v = ((float4*)w)[tid];
  float s = v.x * v.x + v.y * v.y + v.z * v.z + v.w * v.w;
  #pragma unroll
  for (int m = 1; m < 64; m <<= 1) s += __shfl_xor(s, m, 64);
  __shared__ float red[4];
  if ((tid & 63) == 0) red[tid >> 6] = s;
  __syncthreads();
  s = red[0] + red[1] + red[2] + red[3];
  float n = sqrtf(fmaxf(s, 1e-15f));
  float f = tanhf(n) / n;
  v.x *= f; v.y *= f; v.z *= f; v.w *= f;
  ((float4*)w)[tid] = v;
}

extern "C" void kernel_launch(void* const* d_in, const int* in_sizes, int n_in,
                              void* d_out, int out_size, void* d_ws, size_t ws_size,
                              hipStream_t stream) {
  (void)in_sizes; (void)n_in; (void)out_size; (void)ws_size;
  const float* q  = (const float*)d_in[0];
  const float* k  = (const float*)d_in[1];
  const float* v  = (const float*)d_in[2];
  const float* zq = (const float*)d_in[3];
  const float* bq = (const float*)d_in[4];
  const float* zk = (const float*)d_in[5];
  const float* bk = (const float*)d_in[6];
  const float* zv = (const float*)d_in[7];
  const float* bv = (const float*)d_in[8];

  unsigned short* Wbf = (unsigned short*)d_ws;                       // 3*BS*E bf16 (25.2 MB)
  unsigned short* Pbf = Wbf + (size_t)3 * BS_ * E_;                  // 3*BS*E bf16 (25.2 MB)
  unsigned short* BhiT = Pbf;                                        // aliases Pbf (dead until normalize)
  unsigned short* BloT = Pbf + (size_t)3 * E_ * E_;
  unsigned short* Xbf = Pbf + (size_t)3 * BS_ * E_;                  // 3*BS*E bf16 (25.2 MB)
  float* HN           = (float*)(Xbf + (size_t)3 * BS_ * E_);        // 3*BS*16 fp32
  float* lamRow       = HN + (size_t)3 * BS_ * H_;
  float* znA          = lamRow + 3 * BS_;
  float* chA          = znA + 3 * E_;
  float* shA          = chA + 3 * E_;
  float* out          = (float*)d_out;

  double lb1 = lgamma(E_ / 2.0) + lgamma(0.5) - lgamma(E_ / 2.0 + 0.5);
  double lb2 = lgamma(D_ / 2.0) + lgamma(0.5) - lgamma(D_ / 2.0 + 0.5);
  float scale = (float)exp(lb1 - lb2);

  hipLaunchKernelGGL(xsplit_kernel, dim3(3 * BS_), dim3(256), 0, stream, q, k, v, Xbf, lamRow);
  hipLaunchKernelGGL(col_stats_kernel, dim3(48), dim3(256), 0, stream,
                     zq, zk, zv, bq, bk, bv, znA, chA, shA);
  hipLaunchKernelGGL(zsplit_kernel, dim3(16, 16, 3), dim3(256), 0, stream, zq, zk, zv, BhiT, BloT);
  hipLaunchKernelGGL(hlinear_mfma_kernel, dim3(8, 32, 3), dim3(256), 0, stream,
                     Xbf, BhiT, BloT, lamRow, znA, chA, shA, Wbf);
  hipLaunchKernelGGL(normalize_kernel, dim3(3 * BS_), dim3(256), 0, stream, Wbf, Pbf, HN);
  hipLaunchKernelGGL(attention_kernel, dim3(S_ / 128, H_, B_), dim3(512), 0, stream, Pbf, HN, out, scale);
  hipLaunchKernelGGL(expmap_kernel, dim3(BS_), dim3(256), 0, stream, out);
}

// Round 8
// 292.496 us; speedup vs baseline: 1.5954x; 1.3485x over previous
//
#include <hip/hip_runtime.h>
#include <cmath>

#define EPSF 1e-7f

constexpr int B_ = 4, S_ = 1024, E_ = 1024, H_ = 16, D_ = 64;
constexpr int BS_ = B_ * S_;   // 4096 rows per matrix

typedef __attribute__((ext_vector_type(8))) short bf16x8;
typedef __attribute__((ext_vector_type(4))) float f32x4;

__device__ inline unsigned int fbits(float f) { union { float f; unsigned int u; } x; x.f = f; return x.u; }
__device__ inline float ubits(unsigned int u) { union { unsigned int u; float f; } x; x.u = u; return x.f; }

__device__ inline unsigned short f2bf(float f) {
  unsigned int u = fbits(f);
  unsigned int r = u + 0x7fffu + ((u >> 16) & 1u);   // RNE
  return (unsigned short)(r >> 16);
}
__device__ inline float bf2f(unsigned short h) { return ubits(((unsigned int)h) << 16); }
__device__ inline float fastrcp(float x) { return __builtin_amdgcn_rcpf(x); }

__device__ inline unsigned int packhi(float a, float b) {
  return (fbits(a) >> 16) | (fbits(b) & 0xFFFF0000u);
}
__device__ inline unsigned int packlo(float a, float b) {
  float la = a - ubits(fbits(a) & 0xFFFF0000u);
  float lb = b - ubits(fbits(b) & 0xFFFF0000u);
  return (fbits(la) >> 16) | (fbits(lb) & 0xFFFF0000u);
}

// async global -> LDS DMA, 16B per lane; LDS dest = wave-uniform base + lane*16
__device__ __forceinline__ void async_ld16(const unsigned short* g, unsigned short* l) {
  __builtin_amdgcn_global_load_lds(
      (const __attribute__((address_space(1))) unsigned int*)g,
      (__attribute__((address_space(3))) unsigned int*)l, 16, 0, 0);
}

// ---------------- kernel 1: x -> RNE bf16 + per-row lambda (fused) ----------------
__global__ __launch_bounds__(256) void xsplit_kernel(
    const float* __restrict__ xq, const float* __restrict__ xk,
    const float* __restrict__ xv, unsigned short* __restrict__ Xbf,
    float* __restrict__ lamRow) {
  const int row = blockIdx.x;                 // 0 .. 3*BS-1
  const float* x = (row < BS_) ? xq : (row < 2 * BS_ ? xk : xv);
  const int r = row & (BS_ - 1);
  const int tid = threadIdx.x;
  float4 v = ((const float4*)(x + (size_t)r * E_))[tid];
  float s = v.x * v.x + v.y * v.y + v.z * v.z + v.w * v.w;
  #pragma unroll
  for (int m = 1; m < 64; m <<= 1) s += __shfl_xor(s, m, 64);
  __shared__ float red[4];
  if ((tid & 63) == 0) red[tid >> 6] = s;
  __syncthreads();
  s = red[0] + red[1] + red[2] + red[3];
  uint2 p;
  p.x = (unsigned int)f2bf(v.x) | ((unsigned int)f2bf(v.y) << 16);
  p.y = (unsigned int)f2bf(v.z) | ((unsigned int)f2bf(v.w) << 16);
  ((uint2*)(Xbf + (size_t)row * E_))[tid] = p;
  if (tid == 0) lamRow[row] = 2.0f / fmaxf(1.0f - s, EPSF);
}

// ---------------- kernel 2a: partial column sums-of-squares of z ----------------
// grid 3*16*8 = 384 blocks; each reduces a 128-row x 64-col slab
__global__ __launch_bounds__(256) void zstat_partial_kernel(
    const float* __restrict__ zq, const float* __restrict__ zk, const float* __restrict__ zv,
    float* __restrict__ Zpart) {
  const int mat = blockIdx.x >> 7;            // /128
  const int rem = blockIdx.x & 127;
  const int ct = rem >> 3, rc = rem & 7;
  const float* z = mat == 0 ? zq : (mat == 1 ? zk : zv);
  const int tid = threadIdx.x;
  const int col = ct * 64 + (tid & 63);
  const int rbase = rc * 128 + (tid >> 6);
  float s = 0.f;
  #pragma unroll 4
  for (int i = 0; i < 32; i++) {
    float t = z[(size_t)(rbase + i * 4) * E_ + col];
    s += t * t;
  }
  __shared__ float red[4][64];
  red[tid >> 6][tid & 63] = s;
  __syncthreads();
  if (tid < 64) {
    float v = red[0][tid] + red[1][tid] + red[2][tid] + red[3][tid];
    Zpart[((size_t)blockIdx.x) * 64 + tid] = v;
  }
}

// ---------------- kernel 2b: finalize zn / cosh / sinh ----------------
// grid 12 blocks x 256: one thread per column (3*1024 total)
__global__ __launch_bounds__(256) void zstat_final_kernel(
    const float* __restrict__ Zpart,
    const float* __restrict__ bq, const float* __restrict__ bk, const float* __restrict__ bv,
    float* __restrict__ znA, float* __restrict__ chA, float* __restrict__ shA) {
  const int idx = blockIdx.x * 256 + threadIdx.x;   // 0..3071
  const int mat = idx >> 10, col = idx & 1023;
  const int ct = col >> 6, cl = col & 63;
  const float* bb = mat == 0 ? bq : (mat == 1 ? bk : bv);
  float s = 0.f;
  #pragma unroll
  for (int rc = 0; rc < 8; rc++)
    s += Zpart[(size_t)(((mat * 16 + ct) * 8 + rc)) * 64 + cl];
  float n = fmaxf(sqrtf(s), 1e-15f);
  znA[idx] = n;
  float rb = bb[col];
  chA[idx] = coshf(2.f * rb);
  shA[idx] = sinhf(2.f * rb);
}

// ---------------- kernel 2c: transpose + hi/lo split of z -> BT[n][k] bf16 ----------------
__global__ __launch_bounds__(256) void zsplit_kernel(
    const float* __restrict__ zq, const float* __restrict__ zk, const float* __restrict__ zv,
    unsigned short* __restrict__ BhiT, unsigned short* __restrict__ BloT) {
  const int mat = blockIdx.z;
  const float* z = mat == 0 ? zq : (mat == 1 ? zk : zv);
  const int k0 = blockIdx.y * 64, n0 = blockIdx.x * 64;
  __shared__ float t[64][65];
  const int tid = threadIdx.x;
  {
    int kr = tid >> 4, nc = (tid & 15) * 4;
    #pragma unroll
    for (int i = 0; i < 4; i++) {
      float4 vv = *(const float4*)(z + (size_t)(k0 + kr + i * 16) * E_ + n0 + nc);
      t[kr + i * 16][nc + 0] = vv.x;
      t[kr + i * 16][nc + 1] = vv.y;
      t[kr + i * 16][nc + 2] = vv.z;
      t[kr + i * 16][nc + 3] = vv.w;
    }
  }
  __syncthreads();
  int nr = tid >> 2, kc = (tid & 3) * 16;
  unsigned int ph[8], pl[8];
  #pragma unroll
  for (int p = 0; p < 8; p++) {
    float x0 = t[kc + 2 * p][nr], x1 = t[kc + 2 * p + 1][nr];
    ph[p] = packhi(x0, x1);
    pl[p] = packlo(x0, x1);
  }
  size_t off = (size_t)mat * E_ * E_ + (size_t)(n0 + nr) * E_ + k0 + kc;
  uint4* dh = (uint4*)(BhiT + off);
  uint4* dl = (uint4*)(BloT + off);
  dh[0] = make_uint4(ph[0], ph[1], ph[2], ph[3]);
  dh[1] = make_uint4(ph[4], ph[5], ph[6], ph[7]);
  dl[0] = make_uint4(pl[0], pl[1], pl[2], pl[3]);
  dl[1] = make_uint4(pl[4], pl[5], pl[6], pl[7]);
}

// ---------------- kernel 3: 2-term bf16 MFMA GEMM (A*Bhi + A*Blo), async DMA staging ----------------
__global__ __launch_bounds__(256, 3) void hlinear_mfma_kernel(
    const unsigned short* __restrict__ Xbf,
    const unsigned short* __restrict__ BhiT, const unsigned short* __restrict__ BloT,
    const float* __restrict__ lamRow, const float* __restrict__ znA,
    const float* __restrict__ chA, const float* __restrict__ shA,
    unsigned short* __restrict__ Wbf) {
  const int mat = blockIdx.z;
  const unsigned short* xa = Xbf + (size_t)mat * BS_ * E_;
  const unsigned short* bh = BhiT + (size_t)mat * E_ * E_;
  const unsigned short* bl = BloT + (size_t)mat * E_ * E_;
  const int lid = blockIdx.y * 8 + blockIdx.x;   // grid (8, 32, 3)
  const int sqi = lid >> 4, offb = lid & 15;
  const int m0 = ((sqi >> 1) * 4 + (offb & 3)) * 128;
  const int n0 = ((sqi & 1) * 4 + (offb >> 2)) * 128;

  __shared__ unsigned short LDSU[24576];   // 49152 B; epilogue reuses it
  unsigned short* As = LDSU;               // 128 rows x 64 shorts
  unsigned short* Bh = LDSU + 8192;
  unsigned short* Bl = LDSU + 16384;

  const int tid = threadIdx.x;
  const int wid = tid >> 6, lane = tid & 63, quad = lane >> 4, l16 = lane & 15;
  const int wm = (wid >> 1) * 64, wn = (wid & 1) * 64;

  f32x4 acc[4][4];
  #pragma unroll
  for (int i = 0; i < 4; i++)
    #pragma unroll
    for (int j = 0; j < 4; j++) acc[i][j] = (f32x4){0.f, 0.f, 0.f, 0.f};

  const int lrow = lane >> 3;
  const int lcs = ((lane & 7) ^ lrow) * 8;
  const int xsw = (l16 & 7);

  for (int kt = 0; kt < E_ / 64; ++kt) {
    __syncthreads();
    const int kb = kt * 64 + lcs;
    #pragma unroll
    for (int c2 = 0; c2 < 4; c2++) {
      const int c = wid * 4 + c2;
      const int grow = c * 8 + lrow;
      async_ld16(xa + (size_t)(m0 + grow) * E_ + kb, As + c * 512);
      async_ld16(bh + (size_t)(n0 + grow) * E_ + kb, Bh + c * 512);
      async_ld16(bl + (size_t)(n0 + grow) * E_ + kb, Bl + c * 512);
    }
    __syncthreads();
    #pragma unroll
    for (int h = 0; h < 2; h++) {
      bf16x8 a[4];
      #pragma unroll
      for (int mt = 0; mt < 4; mt++) {
        int row = wm + mt * 16 + l16;
        a[mt] = *(const bf16x8*)&As[row * 64 + (((h * 4 + quad) ^ xsw) * 8)];
      }
      #pragma unroll
      for (int nt = 0; nt < 4; nt++) {
        int row = wn + nt * 16 + l16;
        int ro = row * 64 + (((h * 4 + quad) ^ xsw) * 8);
        bf16x8 bhf = *(const bf16x8*)&Bh[ro];
        bf16x8 blf = *(const bf16x8*)&Bl[ro];
        #pragma unroll
        for (int mt = 0; mt < 4; mt++) {
          acc[mt][nt] = __builtin_amdgcn_mfma_f32_16x16x32_bf16(a[mt], bhf, acc[mt][nt], 0, 0, 0);
          acc[mt][nt] = __builtin_amdgcn_mfma_f32_16x16x32_bf16(a[mt], blf, acc[mt][nt], 0, 0, 0);
        }
      }
    }
  }

  // ---- epilogue ----
  const float* lamP = lamRow + mat * BS_;
  float lamv[16];
  #pragma unroll
  for (int mt = 0; mt < 4; mt++)
    #pragma unroll
    for (int r = 0; r < 4; r++)
      lamv[mt * 4 + r] = lamP[m0 + wm + mt * 16 + quad * 4 + r];

  __syncthreads();
  unsigned short* epi = LDSU + wid * 4608;   // 64 rows x 72 shorts
  #pragma unroll
  for (int nt = 0; nt < 4; nt++) {
    int cg = n0 + wn + nt * 16 + l16;
    float zn = znA[mat * E_ + cg];
    float chzn = chA[mat * E_ + cg] / zn;
    float sh = shA[mat * E_ + cg];
    float tzn = 2.f * zn;
    #pragma unroll
    for (int mt = 0; mt < 4; mt++) {
      #pragma unroll
      for (int r = 0; r < 4; r++) {
        float lam = lamv[mt * 4 + r];
        float arg = fmaf(lam * acc[mt][nt][r], chzn, -(lam - 1.f) * sh);
        float sq2 = sqrtf(fmaf(arg, arg, 1.f));
        float v = tzn * __logf(arg + sq2);
        float ev = __expf(v);
        float w = 0.5f * (ev - fastrcp(ev));
        epi[(mt * 16 + quad * 4 + r) * 72 + nt * 16 + l16] = f2bf(w);
      }
    }
  }
  unsigned short* gout = Wbf + (size_t)mat * BS_ * E_ + (size_t)(m0 + wm) * E_ + n0 + wn;
  const int rrow = lane >> 3, seg = lane & 7;
  #pragma unroll
  for (int i = 0; i < 8; i++) {
    int row = i * 8 + rrow;
    uint4 val = *(const uint4*)&epi[row * 72 + seg * 8];
    *(uint4*)(gout + (size_t)row * E_ + seg * 8) = val;
  }
}

// ---------------- kernel 4: normalize bf16 w -> bf16 P + per-head squared norms ----------------
__global__ __launch_bounds__(256) void normalize_kernel(
    const unsigned short* __restrict__ Wbf, unsigned short* __restrict__ Pbf,
    float* __restrict__ HN) {
  const unsigned short* w = Wbf + (size_t)blockIdx.x * E_;
  int tid = threadIdx.x;
  uint2 wv = ((const uint2*)w)[tid];   // 4 bf16
  float w0 = bf2f((unsigned short)(wv.x & 0xFFFF));
  float w1 = bf2f((unsigned short)(wv.x >> 16));
  float w2 = bf2f((unsigned short)(wv.y & 0xFFFF));
  float w3 = bf2f((unsigned short)(wv.y >> 16));
  float s = w0 * w0 + w1 * w1 + w2 * w2 + w3 * w3;
  #pragma unroll
  for (int m = 1; m < 64; m <<= 1) s += __shfl_xor(s, m, 64);
  __shared__ float red[4];
  if ((tid & 63) == 0) red[tid >> 6] = s;
  __syncthreads();
  s = red[0] + red[1] + red[2] + red[3];
  float t = 1.f / (1.f + sqrtf(1.f + s));
  unsigned short p0 = f2bf(w0 * t), p1 = f2bf(w1 * t), p2 = f2bf(w2 * t), p3 = f2bf(w3 * t);
  uint2 pk;
  pk.x = (unsigned int)p0 | ((unsigned int)p1 << 16);
  pk.y = (unsigned int)p2 | ((unsigned int)p3 << 16);
  ((uint2*)(Pbf + (size_t)blockIdx.x * E_))[tid] = pk;
  float r0 = bf2f(p0), r1 = bf2f(p1), r2 = bf2f(p2), r3 = bf2f(p3);
  float hs = r0 * r0 + r1 * r1 + r2 * r2 + r3 * r3;
  hs += __shfl_xor(hs, 1, 64);
  hs += __shfl_xor(hs, 2, 64);
  hs += __shfl_xor(hs, 4, 64);
  hs += __shfl_xor(hs, 8, 64);
  if ((tid & 15) == 0) HN[(size_t)blockIdx.x * H_ + (tid >> 4)] = hs;
}

// ---------------- kernel 5: MFMA flash hyperbolic attention ----------------
__global__ __launch_bounds__(512) void attention_kernel(
    const unsigned short* __restrict__ Pbf, const float* __restrict__ HN,
    float* __restrict__ TV, float scale) {
  const int qt = blockIdx.x, h = blockIdx.y, b = blockIdx.z;
  const unsigned short* pq = Pbf;
  const unsigned short* pk = Pbf + (size_t)BS_ * E_;
  const unsigned short* pv = Pbf + (size_t)2 * BS_ * E_;
  const float* hnq = HN;
  const float* hnk = HN + (size_t)BS_ * H_;
  const float* hnv = HN + (size_t)2 * BS_ * H_;

  const int tid = threadIdx.x;
  const int wid = tid >> 6, lane = tid & 63;
  const int quad = lane >> 4, l16 = lane & 15;

  __shared__ unsigned short Kbf[64][72];
  __shared__ unsigned short Vt[64][72];
  __shared__ unsigned short Pw[8][16][72];
  __shared__ float k2s[64], romk2s[64], lamLs[64];

  const int qrow0 = qt * 128 + wid * 16;
  const size_t qgrow = ((size_t)(b * S_ + qrow0 + l16)) * E_ + h * 64;
  bf16x8 aq0 = *(const bf16x8*)(pq + qgrow + quad * 8);
  bf16x8 aq1 = *(const bf16x8*)(pq + qgrow + 32 + quad * 8);
  float q2r[4], tromq2[4];
  #pragma unroll
  for (int r2 = 0; r2 < 4; r2++) {
    float q2 = hnq[((size_t)(b * S_ + qrow0 + quad * 4 + r2)) * H_ + h];
    q2r[r2] = q2;
    tromq2[r2] = 2.f * fastrcp(1.f - q2);
  }

  float aWL[4] = {0.f, 0.f, 0.f, 0.f};
  float aW[4]  = {0.f, 0.f, 0.f, 0.f};
  f32x4 accO[4];
  #pragma unroll
  for (int dt = 0; dt < 4; dt++) accO[dt] = (f32x4){0.f, 0.f, 0.f, 0.f};

  for (int kt = 0; kt < S_ / 64; ++kt) {
    __syncthreads();
    {
      int row = tid >> 3, col = (tid & 7) * 8;
      const uint4* src = (const uint4*)(pk + ((size_t)(b * S_ + kt * 64 + row)) * E_ + h * 64 + col);
      *(uint4*)&Kbf[row][col] = *src;
    }
    if (tid < 64) {
      float k2 = hnk[((size_t)(b * S_ + kt * 64 + tid)) * H_ + h];
      k2s[tid] = k2;
      romk2s[tid] = fastrcp(1.f - k2);
      float v2 = hnv[((size_t)(b * S_ + kt * 64 + tid)) * H_ + h];
      lamLs[tid] = 2.f / fmaxf(1.f - v2, EPSF);
    }
    {
      int key = tid & 63, dg = tid >> 6;
      union { uint4 q; unsigned short u[8]; } vv;
      vv.q = *(const uint4*)(pv + ((size_t)(b * S_ + kt * 64 + key)) * E_ + h * 64 + dg * 8);
      #pragma unroll
      for (int d = 0; d < 8; d++)
        Vt[dg * 8 + d][key] = vv.u[d];
    }
    __syncthreads();

    #pragma unroll
    for (int nt = 0; nt < 4; nt++) {
      bf16x8 bk0 = *(const bf16x8*)&Kbf[nt * 16 + l16][quad * 8];
      bf16x8 bk1 = *(const bf16x8*)&Kbf[nt * 16 + l16][32 + quad * 8];
      f32x4 z = (f32x4){0.f, 0.f, 0.f, 0.f};
      f32x4 d0 = __builtin_amdgcn_mfma_f32_16x16x32_bf16(aq0, bk0, z, 0, 0, 0);
      d0 = __builtin_amdgcn_mfma_f32_16x16x32_bf16(aq1, bk1, d0, 0, 0, 0);
      float k2 = k2s[nt * 16 + l16];
      float romk2 = romk2s[nt * 16 + l16];
      float lamL = lamLs[nt * 16 + l16];
      #pragma unroll
      for (int r2 = 0; r2 < 4; r2++) {
        float diff2 = fmaf(-2.f, d0[r2], q2r[r2] + k2);
        float t = fmaxf(diff2 * (tromq2[r2] * romk2), 1e-6f);
        float w = fastrcp((1.f + t) + sqrtf(fmaf(t, t, t + t)));
        float wl = w * lamL;
        Pw[wid][quad * 4 + r2][nt * 16 + l16] = f2bf(wl);
        aWL[r2] += wl;
        aW[r2] += w;
      }
    }
    bf16x8 ap0 = *(const bf16x8*)&Pw[wid][l16][quad * 8];
    bf16x8 ap1 = *(const bf16x8*)&Pw[wid][l16][32 + quad * 8];
    #pragma unroll
    for (int dt = 0; dt < 4; dt++) {
      bf16x8 bv0 = *(const bf16x8*)&Vt[dt * 16 + l16][quad * 8];
      bf16x8 bv1 = *(const bf16x8*)&Vt[dt * 16 + l16][32 + quad * 8];
      accO[dt] = __builtin_amdgcn_mfma_f32_16x16x32_bf16(ap0, bv0, accO[dt], 0, 0, 0);
      accO[dt] = __builtin_amdgcn_mfma_f32_16x16x32_bf16(ap1, bv1, accO[dt], 0, 0, 0);
    }
  }

  #pragma unroll
  for (int r2 = 0; r2 < 4; r2++) {
    float dsum = aWL[r2] - aW[r2];
    dsum += __shfl_xor(dsum, 1, 64);
    dsum += __shfl_xor(dsum, 2, 64);
    dsum += __shfl_xor(dsum, 4, 64);
    dsum += __shfl_xor(dsum, 8, 64);
    float uu[4];
    float su = 0.f;
    #pragma unroll
    for (int dt = 0; dt < 4; dt++) { uu[dt] = accO[dt][r2] / dsum; su += uu[dt] * uu[dt]; }
    su += __shfl_xor(su, 1, 64);
    su += __shfl_xor(su, 2, 64);
    su += __shfl_xor(su, 4, 64);
    su += __shfl_xor(su, 8, 64);
    float g = 1.f / (1.f + sqrtf(fmaxf(1.f - su, EPSF)));
    float n2 = fmaxf(su * g * g, 1e-15f);
    float n = sqrtf(n2);
    float fac = atanhf(fminf(n, 1.f - 1e-6f)) / n * g * scale;
    size_t orow = ((size_t)(b * S_ + qrow0 + quad * 4 + r2)) * E_ + h * 64 + l16;
    #pragma unroll
    for (int dt = 0; dt < 4; dt++) TV[orow + dt * 16] = fac * uu[dt];
  }
}

// ---------------- kernel 6: expmap0 per full E-row, in-place on d_out ----------------
__global__ __launch_bounds__(256) void expmap_kernel(float* __restrict__ TV) {
  float* w = TV + (size_t)blockIdx.x * E_;
  int tid = threadIdx.x;
  float4 v = ((float4*)w)[tid];
  float s = v.x * v.x + v.y * v.y + v.z * v.z + v.w * v.w;
  #pragma unroll
  for (int m = 1; m < 64; m <<= 1) s += __shfl_xor(s, m, 64);
  __shared__ float red[4];
  if ((tid & 63) == 0) red[tid >> 6] = s;
  __syncthreads();
  s = red[0] + red[1] + red[2] + red[3];
  float n = sqrtf(fmaxf(s, 1e-15f));
  float f = tanhf(n) / n;
  v.x *= f; v.y *= f; v.z *= f; v.w *= f;
  ((float4*)w)[tid] = v;
}

extern "C" void kernel_launch(void* const* d_in, const int* in_sizes, int n_in,
                              void* d_out, int out_size, void* d_ws, size_t ws_size,
                              hipStream_t stream) {
  (void)in_sizes; (void)n_in; (void)out_size; (void)ws_size;
  const float* q  = (const float*)d_in[0];
  const float* k  = (const float*)d_in[1];
  const float* v  = (const float*)d_in[2];
  const float* zq = (const float*)d_in[3];
  const float* bq = (const float*)d_in[4];
  const float* zk = (const float*)d_in[5];
  const float* bk = (const float*)d_in[6];
  const float* zv = (const float*)d_in[7];
  const float* bv = (const float*)d_in[8];

  unsigned short* Wbf = (unsigned short*)d_ws;                       // 3*BS*E bf16 (25.2 MB)
  unsigned short* Pbf = Wbf + (size_t)3 * BS_ * E_;                  // 3*BS*E bf16 (25.2 MB)
  unsigned short* BhiT = Pbf;                                        // aliases Pbf (dead until normalize)
  unsigned short* BloT = Pbf + (size_t)3 * E_ * E_;
  unsigned short* Xbf = Pbf + (size_t)3 * BS_ * E_;                  // 3*BS*E bf16 (25.2 MB)
  float* HN           = (float*)(Xbf + (size_t)3 * BS_ * E_);        // 3*BS*16 fp32
  float* lamRow       = HN + (size_t)3 * BS_ * H_;
  float* znA          = lamRow + 3 * BS_;
  float* chA          = znA + 3 * E_;
  float* shA          = chA + 3 * E_;
  float* Zpart        = shA + 3 * E_;                                // 384*64 fp32 (98 KB)
  float* out          = (float*)d_out;

  double lb1 = lgamma(E_ / 2.0) + lgamma(0.5) - lgamma(E_ / 2.0 + 0.5);
  double lb2 = lgamma(D_ / 2.0) + lgamma(0.5) - lgamma(D_ / 2.0 + 0.5);
  float scale = (float)exp(lb1 - lb2);

  hipLaunchKernelGGL(xsplit_kernel, dim3(3 * BS_), dim3(256), 0, stream, q, k, v, Xbf, lamRow);
  hipLaunchKernelGGL(zstat_partial_kernel, dim3(384), dim3(256), 0, stream, zq, zk, zv, Zpart);
  hipLaunchKernelGGL(zstat_final_kernel, dim3(12), dim3(256), 0, stream,
                     Zpart, bq, bk, bv, znA, chA, shA);
  hipLaunchKernelGGL(zsplit_kernel, dim3(16, 16, 3), dim3(256), 0, stream, zq, zk, zv, BhiT, BloT);
  hipLaunchKernelGGL(hlinear_mfma_kernel, dim3(8, 32, 3), dim3(256), 0, stream,
                     Xbf, BhiT, BloT, lamRow, znA, chA, shA, Wbf);
  hipLaunchKernelGGL(normalize_kernel, dim3(3 * BS_), dim3(256), 0, stream, Wbf, Pbf, HN);
  hipLaunchKernelGGL(attention_kernel, dim3(S_ / 128, H_, B_), dim3(512), 0, stream, Pbf, HN, out, scale);
  hipLaunchKernelGGL(expmap_kernel, dim3(BS_), dim3(256), 0, stream, out);
}

// Round 9
// 253.057 us; speedup vs baseline: 1.8441x; 1.1558x over previous
//
#include <hip/hip_runtime.h>
#include <cmath>

#define EPSF 1e-7f

constexpr int B_ = 4, S_ = 1024, E_ = 1024, H_ = 16, D_ = 64;
constexpr int BS_ = B_ * S_;   // 4096 rows per matrix

typedef __attribute__((ext_vector_type(8))) short bf16x8;
typedef __attribute__((ext_vector_type(4))) float f32x4;

__device__ inline unsigned int fbits(float f) { union { float f; unsigned int u; } x; x.f = f; return x.u; }
__device__ inline float ubits(unsigned int u) { union { unsigned int u; float f; } x; x.u = u; return x.f; }

__device__ inline unsigned short f2bf(float f) {
  unsigned int u = fbits(f);
  unsigned int r = u + 0x7fffu + ((u >> 16) & 1u);   // RNE
  return (unsigned short)(r >> 16);
}
__device__ inline float bf2f(unsigned short h) { return ubits(((unsigned int)h) << 16); }
__device__ inline float fastrcp(float x) { return __builtin_amdgcn_rcpf(x); }

__device__ inline unsigned int packhi(float a, float b) {
  return (fbits(a) >> 16) | (fbits(b) & 0xFFFF0000u);
}
__device__ inline unsigned int packlo(float a, float b) {
  float la = a - ubits(fbits(a) & 0xFFFF0000u);
  float lb = b - ubits(fbits(b) & 0xFFFF0000u);
  return (fbits(la) >> 16) | (fbits(lb) & 0xFFFF0000u);
}

// async global -> LDS DMA, 16B/lane; LDS dest = wave-uniform base + lane*16
__device__ __forceinline__ void async_ld16(const unsigned short* g, unsigned short* l) {
  __builtin_amdgcn_global_load_lds(
      (const __attribute__((address_space(1))) unsigned int*)g,
      (__attribute__((address_space(3))) unsigned int*)l, 16, 0, 0);
}

// ---------------- kernel 1: x -> RNE bf16 + per-row lambda (fused) ----------------
__global__ __launch_bounds__(256) void xsplit_kernel(
    const float* __restrict__ xq, const float* __restrict__ xk,
    const float* __restrict__ xv, unsigned short* __restrict__ Xbf,
    float* __restrict__ lamRow) {
  const int row = blockIdx.x;                 // 0 .. 3*BS-1
  const float* x = (row < BS_) ? xq : (row < 2 * BS_ ? xk : xv);
  const int r = row & (BS_ - 1);
  const int tid = threadIdx.x;
  float4 v = ((const float4*)(x + (size_t)r * E_))[tid];
  float s = v.x * v.x + v.y * v.y + v.z * v.z + v.w * v.w;
  #pragma unroll
  for (int m = 1; m < 64; m <<= 1) s += __shfl_xor(s, m, 64);
  __shared__ float red[4];
  if ((tid & 63) == 0) red[tid >> 6] = s;
  __syncthreads();
  s = red[0] + red[1] + red[2] + red[3];
  uint2 p;
  p.x = (unsigned int)f2bf(v.x) | ((unsigned int)f2bf(v.y) << 16);
  p.y = (unsigned int)f2bf(v.z) | ((unsigned int)f2bf(v.w) << 16);
  ((uint2*)(Xbf + (size_t)row * E_))[tid] = p;
  if (tid == 0) lamRow[row] = 2.0f / fmaxf(1.0f - s, EPSF);
}

// ---------------- kernel 2: transpose + hi/lo split of z + partial column sums ----------------
__global__ __launch_bounds__(256) void zsplit_kernel(
    const float* __restrict__ zq, const float* __restrict__ zk, const float* __restrict__ zv,
    unsigned short* __restrict__ BhiT, unsigned short* __restrict__ BloT,
    float* __restrict__ Zpart) {
  const int mat = blockIdx.z;
  const float* z = mat == 0 ? zq : (mat == 1 ? zk : zv);
  const int k0 = blockIdx.y * 64, n0 = blockIdx.x * 64;
  __shared__ float t[64][65];
  __shared__ float sred[64][4];
  const int tid = threadIdx.x;
  {
    int kr = tid >> 4, nc = (tid & 15) * 4;
    #pragma unroll
    for (int i = 0; i < 4; i++) {
      float4 vv = *(const float4*)(z + (size_t)(k0 + kr + i * 16) * E_ + n0 + nc);
      t[kr + i * 16][nc + 0] = vv.x;
      t[kr + i * 16][nc + 1] = vv.y;
      t[kr + i * 16][nc + 2] = vv.z;
      t[kr + i * 16][nc + 3] = vv.w;
    }
  }
  __syncthreads();
  int nr = tid >> 2, kc = (tid & 3) * 16;
  unsigned int ph[8], pl[8];
  float ss = 0.f;
  #pragma unroll
  for (int p = 0; p < 8; p++) {
    float x0 = t[kc + 2 * p][nr], x1 = t[kc + 2 * p + 1][nr];
    ph[p] = packhi(x0, x1);
    pl[p] = packlo(x0, x1);
    ss += x0 * x0 + x1 * x1;
  }
  size_t off = (size_t)mat * E_ * E_ + (size_t)(n0 + nr) * E_ + k0 + kc;
  uint4* dh = (uint4*)(BhiT + off);
  uint4* dl = (uint4*)(BloT + off);
  dh[0] = make_uint4(ph[0], ph[1], ph[2], ph[3]);
  dh[1] = make_uint4(ph[4], ph[5], ph[6], ph[7]);
  dl[0] = make_uint4(pl[0], pl[1], pl[2], pl[3]);
  dl[1] = make_uint4(pl[4], pl[5], pl[6], pl[7]);
  sred[nr][tid & 3] = ss;
  __syncthreads();
  if (tid < 64) {
    float v = sred[tid][0] + sred[tid][1] + sred[tid][2] + sred[tid][3];
    Zpart[(size_t)(mat * 16 + blockIdx.y) * E_ + n0 + tid] = v;
  }
}

// ---------------- kernel 2b: finalize zn / cosh / sinh ----------------
__global__ __launch_bounds__(256) void zstat_final_kernel(
    const float* __restrict__ Zpart,
    const float* __restrict__ bq, const float* __restrict__ bk, const float* __restrict__ bv,
    float* __restrict__ znA, float* __restrict__ chA, float* __restrict__ shA) {
  const int idx = blockIdx.x * 256 + threadIdx.x;   // 0..3071
  const int mat = idx >> 10, col = idx & 1023;
  const float* bb = mat == 0 ? bq : (mat == 1 ? bk : bv);
  float s = 0.f;
  #pragma unroll
  for (int ky = 0; ky < 16; ky++)
    s += Zpart[(size_t)(mat * 16 + ky) * E_ + col];
  float n = fmaxf(sqrtf(s), 1e-15f);
  znA[idx] = n;
  float rb = bb[col];
  chA[idx] = coshf(2.f * rb);
  shA[idx] = sinhf(2.f * rb);
}

// ---------------- kernel 3: 2-term bf16 MFMA GEMM (A*Bhi + A*Blo), async DMA staging ----------------
__global__ __launch_bounds__(256, 3) void hlinear_mfma_kernel(
    const unsigned short* __restrict__ Xbf,
    const unsigned short* __restrict__ BhiT, const unsigned short* __restrict__ BloT,
    const float* __restrict__ lamRow, const float* __restrict__ znA,
    const float* __restrict__ chA, const float* __restrict__ shA,
    unsigned short* __restrict__ Wbf) {
  const int mat = blockIdx.z;
  const unsigned short* xa = Xbf + (size_t)mat * BS_ * E_;
  const unsigned short* bh = BhiT + (size_t)mat * E_ * E_;
  const unsigned short* bl = BloT + (size_t)mat * E_ * E_;
  const int lid = blockIdx.y * 8 + blockIdx.x;   // grid (8, 32, 3)
  const int sqi = lid >> 4, offb = lid & 15;
  const int m0 = ((sqi >> 1) * 4 + (offb & 3)) * 128;
  const int n0 = ((sqi & 1) * 4 + (offb >> 2)) * 128;

  __shared__ unsigned short LDSU[24576];   // 49152 B; epilogue reuses it
  unsigned short* As = LDSU;               // 128 rows x 64 shorts
  unsigned short* Bh = LDSU + 8192;
  unsigned short* Bl = LDSU + 16384;

  const int tid = threadIdx.x;
  const int wid = tid >> 6, lane = tid & 63, quad = lane >> 4, l16 = lane & 15;
  const int wm = (wid >> 1) * 64, wn = (wid & 1) * 64;

  f32x4 acc[4][4];
  #pragma unroll
  for (int i = 0; i < 4; i++)
    #pragma unroll
    for (int j = 0; j < 4; j++) acc[i][j] = (f32x4){0.f, 0.f, 0.f, 0.f};

  const int lrow = lane >> 3;
  const int lcs = ((lane & 7) ^ lrow) * 8;
  const int xsw = (l16 & 7);

  for (int kt = 0; kt < E_ / 64; ++kt) {
    __syncthreads();
    const int kb = kt * 64 + lcs;
    #pragma unroll
    for (int c2 = 0; c2 < 4; c2++) {
      const int c = wid * 4 + c2;
      const int grow = c * 8 + lrow;
      async_ld16(xa + (size_t)(m0 + grow) * E_ + kb, As + c * 512);
      async_ld16(bh + (size_t)(n0 + grow) * E_ + kb, Bh + c * 512);
      async_ld16(bl + (size_t)(n0 + grow) * E_ + kb, Bl + c * 512);
    }
    __syncthreads();
    #pragma unroll
    for (int h = 0; h < 2; h++) {
      bf16x8 a[4];
      #pragma unroll
      for (int mt = 0; mt < 4; mt++) {
        int row = wm + mt * 16 + l16;
        a[mt] = *(const bf16x8*)&As[row * 64 + (((h * 4 + quad) ^ xsw) * 8)];
      }
      #pragma unroll
      for (int nt = 0; nt < 4; nt++) {
        int row = wn + nt * 16 + l16;
        int ro = row * 64 + (((h * 4 + quad) ^ xsw) * 8);
        bf16x8 bhf = *(const bf16x8*)&Bh[ro];
        bf16x8 blf = *(const bf16x8*)&Bl[ro];
        #pragma unroll
        for (int mt = 0; mt < 4; mt++) {
          acc[mt][nt] = __builtin_amdgcn_mfma_f32_16x16x32_bf16(a[mt], bhf, acc[mt][nt], 0, 0, 0);
          acc[mt][nt] = __builtin_amdgcn_mfma_f32_16x16x32_bf16(a[mt], blf, acc[mt][nt], 0, 0, 0);
        }
      }
    }
  }

  const float* lamP = lamRow + mat * BS_;
  float lamv[16];
  #pragma unroll
  for (int mt = 0; mt < 4; mt++)
    #pragma unroll
    for (int r = 0; r < 4; r++)
      lamv[mt * 4 + r] = lamP[m0 + wm + mt * 16 + quad * 4 + r];

  __syncthreads();
  unsigned short* epi = LDSU + wid * 4608;   // 64 rows x 72 shorts
  #pragma unroll
  for (int nt = 0; nt < 4; nt++) {
    int cg = n0 + wn + nt * 16 + l16;
    float zn = znA[mat * E_ + cg];
    float chzn = chA[mat * E_ + cg] / zn;
    float sh = shA[mat * E_ + cg];
    float tzn = 2.f * zn;
    #pragma unroll
    for (int mt = 0; mt < 4; mt++) {
      #pragma unroll
      for (int r = 0; r < 4; r++) {
        float lam = lamv[mt * 4 + r];
        float arg = fmaf(lam * acc[mt][nt][r], chzn, -(lam - 1.f) * sh);
        float sq2 = sqrtf(fmaf(arg, arg, 1.f));
        float v = tzn * __logf(arg + sq2);
        float ev = __expf(v);
        float w = 0.5f * (ev - fastrcp(ev));
        epi[(mt * 16 + quad * 4 + r) * 72 + nt * 16 + l16] = f2bf(w);
      }
    }
  }
  unsigned short* gout = Wbf + (size_t)mat * BS_ * E_ + (size_t)(m0 + wm) * E_ + n0 + wn;
  const int rrow = lane >> 3, seg = lane & 7;
  #pragma unroll
  for (int i = 0; i < 8; i++) {
    int row = i * 8 + rrow;
    uint4 val = *(const uint4*)&epi[row * 72 + seg * 8];
    *(uint4*)(gout + (size_t)row * E_ + seg * 8) = val;
  }
}

// ---------------- kernel 4: normalize bf16 w -> bf16 P + per-head squared norms ----------------
__global__ __launch_bounds__(256) void normalize_kernel(
    const unsigned short* __restrict__ Wbf, unsigned short* __restrict__ Pbf,
    float* __restrict__ HN) {
  const unsigned short* w = Wbf + (size_t)blockIdx.x * E_;
  int tid = threadIdx.x;
  uint2 wv = ((const uint2*)w)[tid];   // 4 bf16
  float w0 = bf2f((unsigned short)(wv.x & 0xFFFF));
  float w1 = bf2f((unsigned short)(wv.x >> 16));
  float w2 = bf2f((unsigned short)(wv.y & 0xFFFF));
  float w3 = bf2f((unsigned short)(wv.y >> 16));
  float s = w0 * w0 + w1 * w1 + w2 * w2 + w3 * w3;
  #pragma unroll
  for (int m = 1; m < 64; m <<= 1) s += __shfl_xor(s, m, 64);
  __shared__ float red[4];
  if ((tid & 63) == 0) red[tid >> 6] = s;
  __syncthreads();
  s = red[0] + red[1] + red[2] + red[3];
  float t = 1.f / (1.f + sqrtf(1.f + s));
  unsigned short p0 = f2bf(w0 * t), p1 = f2bf(w1 * t), p2 = f2bf(w2 * t), p3 = f2bf(w3 * t);
  uint2 pk;
  pk.x = (unsigned int)p0 | ((unsigned int)p1 << 16);
  pk.y = (unsigned int)p2 | ((unsigned int)p3 << 16);
  ((uint2*)(Pbf + (size_t)blockIdx.x * E_))[tid] = pk;
  float r0 = bf2f(p0), r1 = bf2f(p1), r2 = bf2f(p2), r3 = bf2f(p3);
  float hs = r0 * r0 + r1 * r1 + r2 * r2 + r3 * r3;
  hs += __shfl_xor(hs, 1, 64);
  hs += __shfl_xor(hs, 2, 64);
  hs += __shfl_xor(hs, 4, 64);
  hs += __shfl_xor(hs, 8, 64);
  if ((tid & 15) == 0) HN[(size_t)blockIdx.x * H_ + (tid >> 4)] = hs;
}

// ---------------- kernel 4b: V head-transpose with lambda folded + lamM (lam-1) bf16 ----------------
// VtG[(b*H+h)*64 + d][s] = bf16(lam(b,h,s) * v_d);  lamMG[(b*H+h)*S + s] = bf16(lam-1)
__global__ __launch_bounds__(256) void vtrans_kernel(
    const unsigned short* __restrict__ Pbf, const float* __restrict__ HN,
    unsigned short* __restrict__ VtG, unsigned short* __restrict__ lamMG) {
  const int st = blockIdx.x, h = blockIdx.y, b = blockIdx.z;
  const unsigned short* pv = Pbf + (size_t)2 * BS_ * E_;
  const float* hnv = HN + (size_t)2 * BS_ * H_;
  __shared__ unsigned short T[64][72];
  __shared__ float lamS[64];
  const int tid = threadIdx.x;
  {
    int lr = tid >> 2, lc = (tid & 3) * 16;
    const uint4* src = (const uint4*)(pv + (size_t)(b * S_ + st * 64 + lr) * E_ + h * 64 + lc);
    *(uint4*)&T[lr][lc] = src[0];
    *(uint4*)&T[lr][lc + 8] = src[1];
  }
  if (tid < 64) {
    float v2 = hnv[(size_t)(b * S_ + st * 64 + tid) * H_ + h];
    float lam = 2.f / fmaxf(1.f - v2, EPSF);
    lamS[tid] = lam;
    lamMG[(size_t)(b * H_ + h) * S_ + st * 64 + tid] = f2bf(lam - 1.f);
  }
  __syncthreads();
  int d = tid >> 2, sc = (tid & 3) * 16;
  unsigned int o[8];
  #pragma unroll
  for (int i = 0; i < 8; i++) {
    int s0 = sc + 2 * i;
    float f0 = bf2f(T[s0][d]) * lamS[s0];
    float f1 = bf2f(T[s0 + 1][d]) * lamS[s0 + 1];
    o[i] = (unsigned int)f2bf(f0) | ((unsigned int)f2bf(f1) << 16);
  }
  unsigned short* dst = VtG + (size_t)((b * H_ + h) * 64 + d) * S_ + st * 64 + sc;
  ((uint4*)dst)[0] = make_uint4(o[0], o[1], o[2], o[3]);
  ((uint4*)dst)[1] = make_uint4(o[4], o[5], o[6], o[7]);
}

// ---------------- kernel 5: MFMA flash hyperbolic attention (DMA-staged, MFMA dnm) ----------------
// w = exp(-acosh(1+t)) = A - sqrt(A^2-1), A = 1+t  (no rcp). dnm via MFMA with lamM broadcast B.
__global__ __launch_bounds__(512) void attention_kernel(
    const unsigned short* __restrict__ Pbf, const float* __restrict__ HN,
    const unsigned short* __restrict__ VtG, const unsigned short* __restrict__ lamMG,
    float* __restrict__ TV, float scale) {
  const int qt = blockIdx.x, h = blockIdx.y, b = blockIdx.z;
  const unsigned short* pq = Pbf;
  const unsigned short* pk = Pbf + (size_t)BS_ * E_;
  const float* hnq = HN;
  const float* hnk = HN + (size_t)BS_ * H_;

  const int tid = threadIdx.x;
  const int wid = tid >> 6, lane = tid & 63;
  const int quad = lane >> 4, l16 = lane & 15;

  __shared__ __align__(16) unsigned short Kl[4096];     // [key][chunk-xor-swizzled], 64x64
  __shared__ __align__(16) unsigned short Vl[4096];     // [dim][chunk-xor-swizzled], 64x64
  __shared__ __align__(16) unsigned short Pw[8][16][72];
  __shared__ float k2s[64], romk2s[64];
  __shared__ __align__(16) unsigned short lamM16[64];

  const int qrow0 = qt * 128 + wid * 16;
  const size_t qgrow = ((size_t)(b * S_ + qrow0 + l16)) * E_ + h * 64;
  bf16x8 aq0 = *(const bf16x8*)(pq + qgrow + quad * 8);
  bf16x8 aq1 = *(const bf16x8*)(pq + qgrow + 32 + quad * 8);
  float q2r[4], tromq2[4];
  #pragma unroll
  for (int r2 = 0; r2 < 4; r2++) {
    float q2 = hnq[((size_t)(b * S_ + qrow0 + quad * 4 + r2)) * H_ + h];
    q2r[r2] = q2;
    tromq2[r2] = 2.f * fastrcp(1.f - q2);
  }

  f32x4 accO[4];
  #pragma unroll
  for (int dt = 0; dt < 4; dt++) accO[dt] = (f32x4){0.f, 0.f, 0.f, 0.f};
  f32x4 accD = (f32x4){0.f, 0.f, 0.f, 0.f};

  const int lr = lane >> 3, cch = lane & 7;
  const int xsw = l16 & 7;
  const unsigned short* kbase = pk + (size_t)(b * S_) * E_ + h * 64;
  const unsigned short* vbase = VtG + (size_t)(b * H_ + h) * 64 * S_;
  const unsigned short* lbase = lamMG + (size_t)(b * H_ + h) * S_;

  for (int kt = 0; kt < S_ / 64; ++kt) {
    __syncthreads();
    {
      const int r = wid * 8 + lr;                    // K: key row / V: dim row
      const int cc = ((cch ^ (r & 7)) * 8);
      async_ld16(kbase + (size_t)(kt * 64 + r) * E_ + cc, Kl + wid * 512);
      async_ld16(vbase + (size_t)r * S_ + kt * 64 + cc, Vl + wid * 512);
    }
    if (tid < 64) {
      float k2 = hnk[((size_t)(b * S_ + kt * 64 + tid)) * H_ + h];
      k2s[tid] = k2;
      romk2s[tid] = fastrcp(1.f - k2);
      lamM16[tid] = lbase[kt * 64 + tid];
    }
    __syncthreads();

    // ---- scores: QK^T MFMA + algebraic weight, trunc-bf16 into Pw ----
    #pragma unroll
    for (int nt = 0; nt < 4; nt++) {
      const int krow = nt * 16 + l16;
      bf16x8 bk0 = *(const bf16x8*)&Kl[krow * 64 + ((quad ^ xsw) * 8)];
      bf16x8 bk1 = *(const bf16x8*)&Kl[krow * 64 + (((4 + quad) ^ xsw) * 8)];
      f32x4 z = (f32x4){0.f, 0.f, 0.f, 0.f};
      f32x4 d0 = __builtin_amdgcn_mfma_f32_16x16x32_bf16(aq0, bk0, z, 0, 0, 0);
      d0 = __builtin_amdgcn_mfma_f32_16x16x32_bf16(aq1, bk1, d0, 0, 0, 0);
      float k2 = k2s[krow], romk2 = romk2s[krow];
      #pragma unroll
      for (int r2 = 0; r2 < 4; r2++) {
        float diff2 = fmaf(-2.f, d0[r2], q2r[r2] + k2);
        float t = fmaxf(diff2 * (tromq2[r2] * romk2), 1e-6f);
        float A = 1.f + t;
        float w = A - sqrtf(fmaf(A, A, -1.f));
        Pw[wid][quad * 4 + r2][krow] = (unsigned short)(fbits(w) >> 16);
      }
    }
    // ---- PV + dnm via MFMA ----
    bf16x8 ap0 = *(const bf16x8*)&Pw[wid][l16][quad * 8];
    bf16x8 ap1 = *(const bf16x8*)&Pw[wid][l16][32 + quad * 8];
    #pragma unroll
    for (int dt = 0; dt < 4; dt++) {
      const int drow = dt * 16 + l16;
      bf16x8 bv0 = *(const bf16x8*)&Vl[drow * 64 + ((quad ^ xsw) * 8)];
      bf16x8 bv1 = *(const bf16x8*)&Vl[drow * 64 + (((4 + quad) ^ xsw) * 8)];
      accO[dt] = __builtin_amdgcn_mfma_f32_16x16x32_bf16(ap0, bv0, accO[dt], 0, 0, 0);
      accO[dt] = __builtin_amdgcn_mfma_f32_16x16x32_bf16(ap1, bv1, accO[dt], 0, 0, 0);
    }
    bf16x8 bl0 = *(const bf16x8*)&lamM16[quad * 8];        // broadcast (same addr per quad)
    bf16x8 bl1 = *(const bf16x8*)&lamM16[32 + quad * 8];
    accD = __builtin_amdgcn_mfma_f32_16x16x32_bf16(ap0, bl0, accD, 0, 0, 0);
    accD = __builtin_amdgcn_mfma_f32_16x16x32_bf16(ap1, bl1, accD, 0, 0, 0);
  }

  // ---- finalize: u = num/dnm; midpoint; logmap0*scale ----
  #pragma unroll
  for (int r2 = 0; r2 < 4; r2++) {
    float rdsum = 1.f / accD[r2];                          // dnm >= 1 (lam-1 >= 1)
    float uu[4];
    float su = 0.f;
    #pragma unroll
    for (int dt = 0; dt < 4; dt++) { uu[dt] = accO[dt][r2] * rdsum; su += uu[dt] * uu[dt]; }
    su += __shfl_xor(su, 1, 64);
    su += __shfl_xor(su, 2, 64);
    su += __shfl_xor(su, 4, 64);
    su += __shfl_xor(su, 8, 64);
    float g = 1.f / (1.f + sqrtf(fmaxf(1.f - su, EPSF)));
    float n2 = fmaxf(su * g * g, 1e-15f);
    float n = sqrtf(n2);
    float fac = atanhf(fminf(n, 1.f - 1e-6f)) / n * g * scale;
    size_t orow = ((size_t)(b * S_ + qrow0 + quad * 4 + r2)) * E_ + h * 64 + l16;
    #pragma unroll
    for (int dt = 0; dt < 4; dt++) TV[orow + dt * 16] = fac * uu[dt];
  }
}

// ---------------- kernel 6: expmap0 per full E-row, in-place on d_out ----------------
__global__ __launch_bounds__(256) void expmap_kernel(float* __restrict__ TV) {
  float* w = TV + (size_t)blockIdx.x * E_;
  int tid = threadIdx.x;
  float4 v = ((float4*)w)[tid];
  float s = v.x * v.x + v.y * v.y + v.z * v.z + v.w * v.w;
  #pragma unroll
  for (int m = 1; m < 64; m <<= 1) s += __shfl_xor(s, m, 64);
  __shared__ float red[4];
  if ((tid & 63) == 0) red[tid >> 6] = s;
  __syncthreads();
  s = red[0] + red[1] + red[2] + red[3];
  float n = sqrtf(fmaxf(s, 1e-15f));
  float f = tanhf(n) / n;
  v.x *= f; v.y *= f; v.z *= f; v.w *= f;
  ((float4*)w)[tid] = v;
}

extern "C" void kernel_launch(void* const* d_in, const int* in_sizes, int n_in,
                              void* d_out, int out_size, void* d_ws, size_t ws_size,
                              hipStream_t stream) {
  (void)in_sizes; (void)n_in; (void)out_size; (void)ws_size;
  const float* q  = (const float*)d_in[0];
  const float* k  = (const float*)d_in[1];
  const float* v  = (const float*)d_in[2];
  const float* zq = (const float*)d_in[3];
  const float* bq = (const float*)d_in[4];
  const float* zk = (const float*)d_in[5];
  const float* bk = (const float*)d_in[6];
  const float* zv = (const float*)d_in[7];
  const float* bv = (const float*)d_in[8];

  unsigned short* Wbf = (unsigned short*)d_ws;                       // 3*BS*E bf16 (25.2 MB)
  unsigned short* Pbf = Wbf + (size_t)3 * BS_ * E_;                  // 3*BS*E bf16 (25.2 MB)
  unsigned short* BhiT = Pbf;                                        // aliases Pbf (dead until normalize)
  unsigned short* BloT = Pbf + (size_t)3 * E_ * E_;
  unsigned short* Xbf = Pbf + (size_t)3 * BS_ * E_;                  // 3*BS*E bf16 (25.2 MB)
  float* HN           = (float*)(Xbf + (size_t)3 * BS_ * E_);        // 3*BS*16 fp32
  float* lamRow       = HN + (size_t)3 * BS_ * H_;
  float* znA          = lamRow + 3 * BS_;
  float* chA          = znA + 3 * E_;
  float* shA          = chA + 3 * E_;
  float* Zpart        = shA + 3 * E_;                                // 3*16*1024 fp32 (196 KB)
  unsigned short* VtG = (unsigned short*)(Zpart + 48 * E_);          // B*H*64*S bf16 (8.4 MB)
  unsigned short* lamMG = VtG + (size_t)B_ * H_ * 64 * S_;           // B*H*S bf16 (128 KB)
  float* out          = (float*)d_out;

  double lb1 = lgamma(E_ / 2.0) + lgamma(0.5) - lgamma(E_ / 2.0 + 0.5);
  double lb2 = lgamma(D_ / 2.0) + lgamma(0.5) - lgamma(D_ / 2.0 + 0.5);
  float scale = (float)exp(lb1 - lb2);

  hipLaunchKernelGGL(xsplit_kernel, dim3(3 * BS_), dim3(256), 0, stream, q, k, v, Xbf, lamRow);
  hipLaunchKernelGGL(zsplit_kernel, dim3(16, 16, 3), dim3(256), 0, stream,
                     zq, zk, zv, BhiT, BloT, Zpart);
  hipLaunchKernelGGL(zstat_final_kernel, dim3(12), dim3(256), 0, stream,
                     Zpart, bq, bk, bv, znA, chA, shA);
  hipLaunchKernelGGL(hlinear_mfma_kernel, dim3(8, 32, 3), dim3(256), 0, stream,
                     Xbf, BhiT, BloT, lamRow, znA, chA, shA, Wbf);
  hipLaunchKernelGGL(normalize_kernel, dim3(3 * BS_), dim3(256), 0, stream, Wbf, Pbf, HN);
  hipLaunchKernelGGL(vtrans_kernel, dim3(16, 16, 4), dim3(256), 0, stream, Pbf, HN, VtG, lamMG);
  hipLaunchKernelGGL(attention_kernel, dim3(S_ / 128, H_, B_), dim3(512), 0, stream,
                     Pbf, HN, VtG, lamMG, out, scale);
  hipLaunchKernelGGL(expmap_kernel, dim3(BS_), dim3(256), 0, stream, out);
}